// Round 12
// baseline (3575.739 us; speedup 1.0000x reference)
//
#include <hip/hip_runtime.h>
#include <math.h>
#include <type_traits>

#define BATCH 8
#define EPS 1e-5f

__device__ __forceinline__ int refl(int p, int n){ return p<0 ? -p : (p>=n ? 2*n-2-p : p); }

// stat layout per layer: stat[(b*C + c)*2] = sum, +1 = sumsq (atomic-accumulated)

// ---------------- conv_in: 3->16, 7x7, reflect pad 3, 512x512, COT=16, PX=4 ----------------
__global__ __launch_bounds__(256) void conv7_in_t(const float* __restrict__ in,
    const float* __restrict__ w, const float* __restrict__ bias, float* __restrict__ out,
    float* __restrict__ statOut){
  const int H=512, W=512;
  __shared__ float wsm[3*49*16];
  __shared__ float bsm[16];
  __shared__ float red[4][32];
  for (int t=threadIdx.x; t<2352; t+=256){
    int j = t & 15; int r = t >> 4;
    wsm[t] = w[j*147 + r];
  }
  if (threadIdx.x < 16) bsm[threadIdx.x] = bias[threadIdx.x];
  __syncthreads();
  int idx = blockIdx.x*256 + threadIdx.x;
  int xq = idx & 127; int y = (idx >> 7) & 511; int b = idx >> 16;
  int x0 = xq*4;
  bool colInt = (xq >= 1) && (xq <= 126);
  int ry[7];
  #pragma unroll
  for (int k=0;k<7;k++) ry[k]=refl(y+k-3,H);
  float acc[16][4];
  #pragma unroll
  for (int j=0;j<16;j++){ float bv=bsm[j];
    #pragma unroll
    for (int p=0;p<4;p++) acc[j][p]=bv; }
  const float* inb = in + (size_t)b*3*H*W;

  auto run = [&](auto INTC){
    constexpr bool INT = decltype(INTC)::value;
    int rx[10];
    if constexpr (!INT){
      #pragma unroll
      for (int q=0;q<10;q++) rx[q]=refl(x0+q-3,W);
    }
    for (int ci=0; ci<3; ++ci){
      const float* ipc = inb + ci*H*W;
      #pragma unroll
      for (int ky=0; ky<7; ++ky){
        const float* row = ipc + ry[ky]*W;
        float rv[10];
        if constexpr (INT){
          rv[0] = row[x0-3];
          float2 a = *(const float2*)(row + x0-2);
          float4 c = *(const float4*)(row + x0);
          float2 d = *(const float2*)(row + x0+4);
          rv[1]=a.x; rv[2]=a.y;
          rv[3]=c.x; rv[4]=c.y; rv[5]=c.z; rv[6]=c.w;
          rv[7]=d.x; rv[8]=d.y;
          rv[9] = row[x0+6];
        } else {
          #pragma unroll
          for (int q=0;q<10;q++) rv[q] = row[rx[q]];
        }
        #pragma unroll
        for (int kx=0; kx<7; ++kx){
          const float4* wp = (const float4*)&wsm[(ci*49+ky*7+kx)*16];
          float4 w0=wp[0], w1=wp[1], w2=wp[2], w3=wp[3];
          float wv[16] = {w0.x,w0.y,w0.z,w0.w, w1.x,w1.y,w1.z,w1.w,
                          w2.x,w2.y,w2.z,w2.w, w3.x,w3.y,w3.z,w3.w};
          #pragma unroll
          for (int p=0;p<4;p++){
            float iv = rv[kx+p];
            #pragma unroll
            for (int j=0;j<16;j++) acc[j][p] = fmaf(iv, wv[j], acc[j][p]);
          }
        }
      }
    }
  };
  if (colInt) run(std::true_type{}); else run(std::false_type{});

  float* ob = out + ((size_t)(b*16)*H + y)*W + x0;
  #pragma unroll
  for (int j=0;j<16;j++){
    float4 v = {acc[j][0],acc[j][1],acc[j][2],acc[j][3]};
    *(float4*)(ob + (size_t)j*H*W) = v;
  }
  // ---- stats ----
  float ss[16], qq[16];
  #pragma unroll
  for (int j=0;j<16;j++){
    float a=0.f,c=0.f;
    #pragma unroll
    for (int p=0;p<4;p++){ a+=acc[j][p]; c=fmaf(acc[j][p],acc[j][p],c); }
    ss[j]=a; qq[j]=c;
  }
  #pragma unroll
  for (int o=32;o>0;o>>=1){
    #pragma unroll
    for (int j=0;j<16;j++){ ss[j]+=__shfl_down(ss[j],o); qq[j]+=__shfl_down(qq[j],o); }
  }
  int lane = threadIdx.x & 63, wid = threadIdx.x >> 6;
  if (lane==0){
    #pragma unroll
    for (int j=0;j<16;j++){ red[wid][j]=ss[j]; red[wid][16+j]=qq[j]; }
  }
  __syncthreads();
  if (threadIdx.x < 16){
    int j = threadIdx.x;
    float a = red[0][j]+red[1][j]+red[2][j]+red[3][j];
    float c = red[0][16+j]+red[1][16+j]+red[2][16+j]+red[3][16+j];
    float* sp = &statOut[((size_t)b*16 + j)*2];
    atomicAdd(sp, a); atomicAdd(sp+1, c);
  }
}

// ---------------- conv_out: 16->3, 7x7 reflect, tanh, PX=8; normalizes input ----------------
__global__ __launch_bounds__(256) void conv7_out_t(const float* __restrict__ in,
    const float* __restrict__ w, const float* __restrict__ bias, float* __restrict__ out,
    const float* __restrict__ statIn){
  const int H=512, W=512;
  __shared__ float wsm[16*49*3];
  __shared__ float bsm[3];
  __shared__ float msm[16], ism[16];
  for (int t=threadIdx.x; t<2352; t+=256){
    int j = t % 3; int r = t / 3;
    wsm[t] = w[j*784 + r];
  }
  if (threadIdx.x < 3) bsm[threadIdx.x] = bias[threadIdx.x];
  int idx = blockIdx.x*256 + threadIdx.x;
  int xq = idx & 63; int y = (idx >> 6) & 511; int b = idx >> 15;
  if (threadIdx.x < 16){
    const float invHW = 1.f/(512.f*512.f);
    float s  = statIn[((size_t)b*16 + threadIdx.x)*2];
    float s2 = statIn[((size_t)b*16 + threadIdx.x)*2+1];
    float m = s*invHW;
    float v = fmaxf(s2*invHW - m*m, 0.f);
    msm[threadIdx.x] = m; ism[threadIdx.x] = rsqrtf(v + EPS);
  }
  __syncthreads();
  int x0 = xq*8;
  bool colInt = (xq >= 1) && (xq <= 62);
  int ry[7];
  #pragma unroll
  for (int k=0;k<7;k++) ry[k]=refl(y+k-3,H);
  float acc[3][8];
  #pragma unroll
  for (int j=0;j<3;j++){ float bv=bsm[j];
    #pragma unroll
    for (int p=0;p<8;p++) acc[j][p]=bv; }
  const float* inb = in + (size_t)b*16*H*W;

  auto run = [&](auto INTC){
    constexpr bool INT = decltype(INTC)::value;
    int rx[14];
    if constexpr (!INT){
      #pragma unroll
      for (int q=0;q<14;q++) rx[q]=refl(x0+q-3,W);
    }
    for (int ci=0; ci<16; ++ci){
      const float* ipc = inb + (size_t)ci*H*W;
      float m = msm[ci], is = ism[ci];
      #pragma unroll
      for (int ky=0; ky<7; ++ky){
        const float* row = ipc + ry[ky]*W;
        float rv[14];
        if constexpr (INT){
          rv[0] = row[x0-3];
          float2 a = *(const float2*)(row + x0-2);
          float4 c = *(const float4*)(row + x0);
          float4 d = *(const float4*)(row + x0+4);
          float2 e = *(const float2*)(row + x0+8);
          rv[1]=a.x; rv[2]=a.y;
          rv[3]=c.x; rv[4]=c.y; rv[5]=c.z; rv[6]=c.w;
          rv[7]=d.x; rv[8]=d.y; rv[9]=d.z; rv[10]=d.w;
          rv[11]=e.x; rv[12]=e.y;
          rv[13] = row[x0+10];
        } else {
          #pragma unroll
          for (int q=0;q<14;q++) rv[q] = row[rx[q]];
        }
        #pragma unroll
        for (int q=0;q<14;q++) rv[q] = fmaxf((rv[q]-m)*is, 0.f);
        #pragma unroll
        for (int kx=0; kx<7; ++kx){
          const float* wp = &wsm[(ci*49+ky*7+kx)*3];
          float w0=wp[0], w1=wp[1], w2=wp[2];
          #pragma unroll
          for (int p=0;p<8;p++){
            float iv = rv[kx+p];
            acc[0][p] = fmaf(iv, w0, acc[0][p]);
            acc[1][p] = fmaf(iv, w1, acc[1][p]);
            acc[2][p] = fmaf(iv, w2, acc[2][p]);
          }
        }
      }
    }
  };
  if (colInt) run(std::true_type{}); else run(std::false_type{});

  float* ob = out + ((size_t)(b*3)*H + y)*W + x0;
  #pragma unroll
  for (int j=0;j<3;j++){
    float4 v0 = {tanhf(acc[j][0]),tanhf(acc[j][1]),tanhf(acc[j][2]),tanhf(acc[j][3])};
    float4 v1 = {tanhf(acc[j][4]),tanhf(acc[j][5]),tanhf(acc[j][6]),tanhf(acc[j][7])};
    *(float4*)(ob + (size_t)j*H*W)     = v0;
    *(float4*)(ob + (size_t)j*H*W + 4) = v1;
  }
}

// ---------------- 3x3 stride-2 conv, pad 1; normalizes input, emits stats ----------------
// Scalar (s_load) weights via wave-uniform index; optional 2-deep ci software pipeline.
template<int CIN, int COT, int PX, bool PIPE>
__global__ __launch_bounds__(256,4) void conv3s2_t(const float* __restrict__ in,
    const float* __restrict__ w, const float* __restrict__ bias, float* __restrict__ out,
    int Hin, int Win, const float* __restrict__ statIn, float* __restrict__ statOut){
  const int Cout = 2*CIN;
  __shared__ float msm[CIN], ism[CIN];
  __shared__ float red[4][2*COT];
  int Hout = Hin>>1, Wout = Win>>1, WQ = Wout/PX;
  int idx = blockIdx.x*256 + threadIdx.x;
  int xq = idx % WQ; int t = idx / WQ;
  int y  = t % Hout;  t /= Hout;
  int cot = t % (Cout/COT); int b = t / (Cout/COT);
  int co0 = __builtin_amdgcn_readfirstlane(cot) * COT;   // wave-uniform
  {
    float invHW = 1.f/(float)(Hin*Win);
    for (int t2=threadIdx.x; t2<CIN; t2+=256){
      float s  = statIn[((size_t)b*CIN + t2)*2];
      float s2 = statIn[((size_t)b*CIN + t2)*2+1];
      float m = s*invHW;
      float v = fmaxf(s2*invHW - m*m, 0.f);
      msm[t2] = m; ism[t2] = rsqrtf(v + EPS);
    }
  }
  __syncthreads();
  int x0 = xq*PX; int ix0 = 2*x0-1; int iy0 = 2*y-1;
  bool colInt = (xq >= 1);
  float acc[COT][PX];
  #pragma unroll
  for (int j=0;j<COT;j++){ float bv = bias[co0+j];
    #pragma unroll
    for (int p=0;p<PX;p++) acc[j][p]=bv; }
  const float* inb = in + (size_t)b*CIN*Hin*Win;

  auto loadci = [&](int ci, float (&rv)[3][2*PX+1]){
    const float* ip = inb + (size_t)ci*Hin*Win;
    float m = msm[ci], is = ism[ci];
    #pragma unroll
    for (int ky=0;ky<3;ky++){
      int iy = iy0+ky;
      bool okY = (unsigned)iy < (unsigned)Hin;
      const float* row = ip + iy*Win;
      if (okY && colInt){
        rv[ky][0] = row[ix0];
        if constexpr (PX>=2){
          float4 a = *(const float4*)(row + ix0+1);
          rv[ky][1]=a.x; rv[ky][2]=a.y; rv[ky][3]=a.z; rv[ky][4]=a.w;
        } else {
          float2 a = *(const float2*)(row + ix0+1);
          rv[ky][1]=a.x; rv[ky][2]=a.y;
        }
        if constexpr (PX==4){
          float4 b4 = *(const float4*)(row + ix0+5);
          rv[ky][5]=b4.x; rv[ky][6]=b4.y; rv[ky][7]=b4.z; rv[ky][8]=b4.w;
        }
        #pragma unroll
        for (int q=0;q<2*PX+1;q++) rv[ky][q] = fmaxf((rv[ky][q]-m)*is, 0.f);
      } else {
        #pragma unroll
        for (int q=0;q<2*PX+1;q++){
          int ix = ix0+q;
          rv[ky][q] = (okY && (unsigned)ix<(unsigned)Win) ? fmaxf((row[ix]-m)*is,0.f) : 0.f;
        }
      }
    }
  };
  auto compci = [&](int ci, float (&rv)[3][2*PX+1]){
    #pragma unroll
    for (int j=0;j<COT;j++){
      const float* wj = w + ((size_t)(co0+j)*CIN + ci)*9;   // uniform -> s_load
      float wk[9];
      #pragma unroll
      for (int k=0;k<9;k++) wk[k] = wj[k];
      #pragma unroll
      for (int p=0;p<PX;p++)
        #pragma unroll
        for (int ky=0;ky<3;ky++)
          #pragma unroll
          for (int kx=0;kx<3;kx++)
            acc[j][p] = fmaf(rv[ky][2*p+kx], wk[ky*3+kx], acc[j][p]);
    }
  };

  if constexpr (PIPE){
    float rvA[3][2*PX+1], rvB[3][2*PX+1];
    loadci(0, rvA);
    for (int ci=0; ci<CIN; ci+=2){
      loadci(ci+1, rvB);
      compci(ci, rvA);
      if (ci+2 < CIN) loadci(ci+2, rvA);
      compci(ci+1, rvB);
    }
  } else {
    for (int ci=0; ci<CIN; ++ci){
      float rv[3][2*PX+1];
      loadci(ci, rv);
      compci(ci, rv);
    }
  }

  float* ob = out + (((size_t)b*Cout + co0)*Hout + y)*Wout + x0;
  #pragma unroll
  for (int j=0;j<COT;j++){
    if constexpr (PX==4){
      float4 v = {acc[j][0],acc[j][1],acc[j][2],acc[j][3]};
      *(float4*)(ob + (size_t)j*Hout*Wout) = v;
    } else if constexpr (PX==2){
      float2 v = {acc[j][0],acc[j][1]};
      *(float2*)(ob + (size_t)j*Hout*Wout) = v;
    } else {
      ob[(size_t)j*Hout*Wout] = acc[j][0];
    }
  }
  // ---- stats ----
  float ss[COT], qq[COT];
  #pragma unroll
  for (int j=0;j<COT;j++){
    float a=0.f,c=0.f;
    #pragma unroll
    for (int p=0;p<PX;p++){ a+=acc[j][p]; c=fmaf(acc[j][p],acc[j][p],c); }
    ss[j]=a; qq[j]=c;
  }
  #pragma unroll
  for (int o=32;o>0;o>>=1){
    #pragma unroll
    for (int j=0;j<COT;j++){ ss[j]+=__shfl_down(ss[j],o); qq[j]+=__shfl_down(qq[j],o); }
  }
  int lane = threadIdx.x & 63, wid = threadIdx.x >> 6;
  if (lane==0){
    #pragma unroll
    for (int j=0;j<COT;j++){ red[wid][j]=ss[j]; red[wid][COT+j]=qq[j]; }
  }
  __syncthreads();
  if (threadIdx.x < COT){
    int j = threadIdx.x;
    float a = red[0][j]+red[1][j]+red[2][j]+red[3][j];
    float c = red[0][COT+j]+red[1][COT+j]+red[2][COT+j]+red[3][COT+j];
    float* sp = &statOut[((size_t)b*Cout + co0 + j)*2];
    atomicAdd(sp, a); atomicAdd(sp+1, c);
  }
}

// ---------------- tconv k=3 s=2 p=1 op=1; scalar weights; 2-deep ci pipeline ----------------
template<int CIN, int COT>
__global__ __launch_bounds__(256,4) void tconv3_t(const float* __restrict__ in,
    const float* __restrict__ w, const float* __restrict__ bias, float* __restrict__ out,
    int Hin, int Win, const float* __restrict__ statIn, float* __restrict__ statOut){
  const int PX=2, Cout = CIN/2;
  __shared__ float msm[CIN], ism[CIN];
  __shared__ float red[4][2*COT];
  int Hout = Hin*2, Wout = Win*2, WQ = Win/PX;
  int idx = blockIdx.x*256 + threadIdx.x;
  int xq = idx % WQ; int t = idx / WQ;
  int yo = t % Hin;  t /= Hin;
  int cot = t % (Cout/COT); int b = t / (Cout/COT);
  int co0 = __builtin_amdgcn_readfirstlane(cot) * COT;  // wave-uniform
  {
    float invHW = 1.f/(float)(Hin*Win);
    for (int t2=threadIdx.x; t2<CIN; t2+=256){
      float s  = statIn[((size_t)b*CIN + t2)*2];
      float s2 = statIn[((size_t)b*CIN + t2)*2+1];
      float m = s*invHW;
      float v = fmaxf(s2*invHW - m*m, 0.f);
      msm[t2] = m; ism[t2] = rsqrtf(v + EPS);
    }
  }
  __syncthreads();
  int xo0 = xq*PX;
  bool okY1 = (yo+1) < Hin;
  bool fast = okY1 && (xo0+2 < Win);
  float acc[COT][2][2*PX];
  #pragma unroll
  for (int j=0;j<COT;j++){ float bv = bias[co0+j];
    #pragma unroll
    for (int oy=0;oy<2;oy++)
      #pragma unroll
      for (int ox=0;ox<2*PX;ox++) acc[j][oy][ox]=bv; }
  const float* inb = in + (size_t)b*CIN*Hin*Win;

  auto loadci = [&](int ci, float (&v)[2][PX+1]){
    const float* ip = inb + (size_t)ci*Hin*Win + (size_t)yo*Win;
    float m = msm[ci], is = ism[ci];
    if (fast){
      float2 a = *(const float2*)(ip + xo0);
      float2 b2 = *(const float2*)(ip + Win + xo0);
      v[0][0]=a.x;  v[0][1]=a.y;  v[0][2]=ip[xo0+2];
      v[1][0]=b2.x; v[1][1]=b2.y; v[1][2]=ip[Win+xo0+2];
      #pragma unroll
      for (int r=0;r<2;r++)
        #pragma unroll
        for (int c=0;c<3;c++) v[r][c] = fmaxf((v[r][c]-m)*is, 0.f);
    } else {
      #pragma unroll
      for (int c=0;c<PX+1;c++){
        int xc = xo0+c; bool okX = xc < Win;
        v[0][c] = okX ? fmaxf((ip[xc]-m)*is,0.f) : 0.f;
        v[1][c] = (okX && okY1) ? fmaxf((ip[Win+xc]-m)*is,0.f) : 0.f;
      }
    }
  };
  auto compci = [&](int ci, float (&v)[2][PX+1]){
    #pragma unroll
    for (int j=0;j<COT;j++){
      const float* wj = w + ((size_t)ci*Cout + co0+j)*9;   // uniform -> s_load
      float wk[9];
      #pragma unroll
      for (int k=0;k<9;k++) wk[k] = wj[k];
      #pragma unroll
      for (int q=0;q<PX;q++){
        float v00=v[0][q], v01=v[0][q+1], v10=v[1][q], v11=v[1][q+1];
        acc[j][0][2*q]   = fmaf(v00, wk[4], acc[j][0][2*q]);
        acc[j][0][2*q+1] = fmaf(v00, wk[5], fmaf(v01, wk[3], acc[j][0][2*q+1]));
        acc[j][1][2*q]   = fmaf(v00, wk[7], fmaf(v10, wk[1], acc[j][1][2*q]));
        acc[j][1][2*q+1] = fmaf(v00, wk[8], fmaf(v01, wk[6],
                           fmaf(v10, wk[2], fmaf(v11, wk[0], acc[j][1][2*q+1]))));
      }
    }
  };

  float vA[2][PX+1], vB[2][PX+1];
  loadci(0, vA);
  for (int ci=0; ci<CIN; ci+=2){
    loadci(ci+1, vB);
    compci(ci, vA);
    if (ci+2 < CIN) loadci(ci+2, vA);
    compci(ci+1, vB);
  }

  float* ob = out + (((size_t)b*Cout + co0)*Hout + 2*yo)*Wout + 2*xo0;
  #pragma unroll
  for (int j=0;j<COT;j++){
    float4 r0 = {acc[j][0][0],acc[j][0][1],acc[j][0][2],acc[j][0][3]};
    float4 r1 = {acc[j][1][0],acc[j][1][1],acc[j][1][2],acc[j][1][3]};
    *(float4*)(ob + (size_t)j*Hout*Wout)        = r0;
    *(float4*)(ob + (size_t)j*Hout*Wout + Wout) = r1;
  }
  // ---- stats ----
  float ss[COT], qq[COT];
  #pragma unroll
  for (int j=0;j<COT;j++){
    float a=0.f,c=0.f;
    #pragma unroll
    for (int oy=0;oy<2;oy++)
      #pragma unroll
      for (int ox=0;ox<2*PX;ox++){ float u=acc[j][oy][ox]; a+=u; c=fmaf(u,u,c); }
    ss[j]=a; qq[j]=c;
  }
  #pragma unroll
  for (int o=32;o>0;o>>=1){
    #pragma unroll
    for (int j=0;j<COT;j++){ ss[j]+=__shfl_down(ss[j],o); qq[j]+=__shfl_down(qq[j],o); }
  }
  int lane = threadIdx.x & 63, wid = threadIdx.x >> 6;
  if (lane==0){
    #pragma unroll
    for (int j=0;j<COT;j++){ red[wid][j]=ss[j]; red[wid][COT+j]=qq[j]; }
  }
  __syncthreads();
  if (threadIdx.x < COT){
    int j = threadIdx.x;
    float a = red[0][j]+red[1][j]+red[2][j]+red[3][j];
    float c = red[0][COT+j]+red[1][COT+j]+red[2][COT+j]+red[3][COT+j];
    float* sp = &statOut[((size_t)b*Cout + co0 + j)*2];
    atomicAdd(sp, a); atomicAdd(sp+1, c);
  }
}

// ---------------- per-(b,id) scatter-mean: accumulate ----------------
__global__ void pool_accum(const float* __restrict__ t, const int* __restrict__ imap,
                           float* __restrict__ sums, float* __restrict__ cnts){
  const int P = 512*512;
  int b = blockIdx.y;
  __shared__ float ls[96];
  __shared__ float lc[32];
  for (int i=threadIdx.x;i<96;i+=blockDim.x) ls[i]=0.f;
  if (threadIdx.x<32) lc[threadIdx.x]=0.f;
  __syncthreads();
  const float* tb = t + (size_t)b*3*P;
  const int*   mb = imap + (size_t)b*P;
  for (int p = blockIdx.x*blockDim.x + threadIdx.x; p < P; p += gridDim.x*blockDim.x){
    int id = mb[p];
    atomicAdd(&ls[id*3+0], tb[p]);
    atomicAdd(&ls[id*3+1], tb[P+p]);
    atomicAdd(&ls[id*3+2], tb[2*P+p]);
    atomicAdd(&lc[id], 1.0f);
  }
  __syncthreads();
  for (int i=threadIdx.x;i<96;i+=blockDim.x) atomicAdd(&sums[b*96+i], ls[i]);
  if (threadIdx.x<32) atomicAdd(&cnts[b*32+threadIdx.x], lc[threadIdx.x]);
}

// ---------------- broadcast means back ----------------
__global__ void pool_bcast(float* __restrict__ out, const int* __restrict__ imap,
                           const float* __restrict__ sums, const float* __restrict__ cnts){
  const int P = 512*512;
  int b = blockIdx.y;
  __shared__ float lm[96];
  if (threadIdx.x < 96){
    int id = threadIdx.x/3;
    lm[threadIdx.x] = sums[b*96+threadIdx.x] / fmaxf(cnts[b*32+id], 1.0f);
  }
  __syncthreads();
  const int* mb = imap + (size_t)b*P;
  float* ob = out + (size_t)b*3*P;
  for (int p = blockIdx.x*blockDim.x + threadIdx.x; p < P; p += gridDim.x*blockDim.x){
    int id = mb[p];
    ob[p]     = lm[id*3+0];
    ob[P+p]   = lm[id*3+1];
    ob[2*P+p] = lm[id*3+2];
  }
}

static inline int cdiv(int a, int b){ return (a+b-1)/b; }

extern "C" void kernel_launch(void* const* d_in, const int* in_sizes, int n_in,
                              void* d_out, int out_size, void* d_ws, size_t ws_size,
                              hipStream_t stream) {
  const float* x    = (const float*)d_in[0];
  const int*   imap = (const int*)d_in[1];
  const float* w_in = (const float*)d_in[2];
  const float* b_in = (const float*)d_in[3];
  const float *wd[4], *bd[4], *wu[4], *bu[4];
  for (int i=0;i<4;i++){ wd[i]=(const float*)d_in[4+2*i];  bd[i]=(const float*)d_in[5+2*i]; }
  for (int i=0;i<4;i++){ wu[i]=(const float*)d_in[12+2*i]; bu[i]=(const float*)d_in[13+2*i]; }
  const float* w_out = (const float*)d_in[20];
  const float* b_out = (const float*)d_in[21];
  float* out = (float*)d_out;

  char* ws = (char*)d_ws;
  float* A     = (float*)ws;
  float* Bb    = (float*)(ws + (size_t)134217728);
  float* stats = (float*)(ws + (size_t)134217728 + (size_t)67108864);
  float* stLin = stats;          // 8*16*2  = 256
  float* std0  = stLin + 256;    // 8*32*2  = 512
  float* std1  = std0  + 512;    // 8*64*2  = 1024
  float* std2  = std1  + 1024;   // 8*128*2 = 2048
  float* std3  = std2  + 2048;   // 8*256*2 = 4096
  float* stu0  = std3  + 4096;   // 8*128*2 = 2048
  float* stu1  = stu0  + 2048;   // 8*64*2  = 1024
  float* stu2  = stu1  + 1024;   // 8*32*2  = 512
  float* stu3  = stu2  + 512;    // 8*16*2  = 256
  float* sums  = stu3  + 256;    // [8][32][3] = 768
  float* cnts  = sums  + 768;    // [8][32]    = 256
  hipMemsetAsync(stats, 0, (size_t)(11776 + 1024)*sizeof(float), stream);

  // conv_in: 3 -> 16 @ 512x512 (raw input, emits stLin)
  conv7_in_t<<<2048, 256, 0, stream>>>(x, w_in, b_in, A, stLin);

  // down path (normalize input via statIn, emit statOut)
  conv3s2_t<16,8,4,false><<<2048, 256, 0, stream>>>(A,  wd[0], bd[0], Bb, 512, 512, stLin, std0);
  conv3s2_t<32,8,4,true><<<1024, 256, 0, stream>>>(Bb, wd[1], bd[1], A,  256, 256, std0, std1);
  conv3s2_t<64,8,4,true><<< 512, 256, 0, stream>>>(A,  wd[2], bd[2], Bb, 128, 128, std1, std2);
  conv3s2_t<128,4,2,true><<<1024, 256, 0, stream>>>(Bb, wd[3], bd[3], A,  64,  64, std2, std3);

  // up path (R10 configs)
  tconv3_t<256,2><<<1024, 256, 0, stream>>>(A,  wu[0], bu[0], Bb, 32, 32, std3, stu0);
  tconv3_t<128,4><<<1024, 256, 0, stream>>>(Bb, wu[1], bu[1], A,  64, 64, stu0, stu1);
  tconv3_t<64,8><<<1024, 256, 0, stream>>>(A,  wu[2], bu[2], Bb, 128, 128, stu1, stu2);
  tconv3_t<32,8><<<2048, 256, 0, stream>>>(Bb, wu[3], bu[3], A,  256, 256, stu2, stu3);

  // conv_out: 16 -> 3 @ 512x512 + tanh (normalizes u3 on load)
  conv7_out_t<<<1024, 256, 0, stream>>>(A, w_out, b_out, out, stu3);

  // scatter-mean pooling over instance ids
  pool_accum<<<dim3(64,BATCH),256,0,stream>>>(out, imap, sums, cnts);
  pool_bcast<<<dim3(128,BATCH),256,0,stream>>>(out, imap, sums, cnts);
}

// Round 13
// 2671.937 us; speedup vs baseline: 1.3383x; 1.3383x over previous
//
#include <hip/hip_runtime.h>
#include <math.h>
#include <type_traits>

#define BATCH 8
#define EPS 1e-5f

__device__ __forceinline__ int refl(int p, int n){ return p<0 ? -p : (p>=n ? 2*n-2-p : p); }

// stat layout per layer: stat[(b*C + c)*2] = sum, +1 = sumsq (atomic-accumulated)

// ---------------- conv_in: 3->16, 7x7, reflect pad 3, 512x512, COT=16, PX=4 ----------------
__global__ __launch_bounds__(256) void conv7_in_t(const float* __restrict__ in,
    const float* __restrict__ w, const float* __restrict__ bias, float* __restrict__ out,
    float* __restrict__ statOut){
  const int H=512, W=512;
  __shared__ float wsm[3*49*16];
  __shared__ float bsm[16];
  __shared__ float red[4][32];
  for (int t=threadIdx.x; t<2352; t+=256){
    int j = t & 15; int r = t >> 4;
    wsm[t] = w[j*147 + r];
  }
  if (threadIdx.x < 16) bsm[threadIdx.x] = bias[threadIdx.x];
  __syncthreads();
  int idx = blockIdx.x*256 + threadIdx.x;
  int xq = idx & 127; int y = (idx >> 7) & 511; int b = idx >> 16;
  int x0 = xq*4;
  bool colInt = (xq >= 1) && (xq <= 126);
  int ry[7];
  #pragma unroll
  for (int k=0;k<7;k++) ry[k]=refl(y+k-3,H);
  float acc[16][4];
  #pragma unroll
  for (int j=0;j<16;j++){ float bv=bsm[j];
    #pragma unroll
    for (int p=0;p<4;p++) acc[j][p]=bv; }
  const float* inb = in + (size_t)b*3*H*W;

  auto run = [&](auto INTC){
    constexpr bool INT = decltype(INTC)::value;
    int rx[10];
    if constexpr (!INT){
      #pragma unroll
      for (int q=0;q<10;q++) rx[q]=refl(x0+q-3,W);
    }
    for (int ci=0; ci<3; ++ci){
      const float* ipc = inb + ci*H*W;
      #pragma unroll
      for (int ky=0; ky<7; ++ky){
        const float* row = ipc + ry[ky]*W;
        float rv[10];
        if constexpr (INT){
          rv[0] = row[x0-3];
          float2 a = *(const float2*)(row + x0-2);
          float4 c = *(const float4*)(row + x0);
          float2 d = *(const float2*)(row + x0+4);
          rv[1]=a.x; rv[2]=a.y;
          rv[3]=c.x; rv[4]=c.y; rv[5]=c.z; rv[6]=c.w;
          rv[7]=d.x; rv[8]=d.y;
          rv[9] = row[x0+6];
        } else {
          #pragma unroll
          for (int q=0;q<10;q++) rv[q] = row[rx[q]];
        }
        #pragma unroll
        for (int kx=0; kx<7; ++kx){
          const float4* wp = (const float4*)&wsm[(ci*49+ky*7+kx)*16];
          float4 w0=wp[0], w1=wp[1], w2=wp[2], w3=wp[3];
          float wv[16] = {w0.x,w0.y,w0.z,w0.w, w1.x,w1.y,w1.z,w1.w,
                          w2.x,w2.y,w2.z,w2.w, w3.x,w3.y,w3.z,w3.w};
          #pragma unroll
          for (int p=0;p<4;p++){
            float iv = rv[kx+p];
            #pragma unroll
            for (int j=0;j<16;j++) acc[j][p] = fmaf(iv, wv[j], acc[j][p]);
          }
        }
      }
    }
  };
  if (colInt) run(std::true_type{}); else run(std::false_type{});

  float* ob = out + ((size_t)(b*16)*H + y)*W + x0;
  #pragma unroll
  for (int j=0;j<16;j++){
    float4 v = {acc[j][0],acc[j][1],acc[j][2],acc[j][3]};
    *(float4*)(ob + (size_t)j*H*W) = v;
  }
  // ---- stats ----
  float ss[16], qq[16];
  #pragma unroll
  for (int j=0;j<16;j++){
    float a=0.f,c=0.f;
    #pragma unroll
    for (int p=0;p<4;p++){ a+=acc[j][p]; c=fmaf(acc[j][p],acc[j][p],c); }
    ss[j]=a; qq[j]=c;
  }
  #pragma unroll
  for (int o=32;o>0;o>>=1){
    #pragma unroll
    for (int j=0;j<16;j++){ ss[j]+=__shfl_down(ss[j],o); qq[j]+=__shfl_down(qq[j],o); }
  }
  int lane = threadIdx.x & 63, wid = threadIdx.x >> 6;
  if (lane==0){
    #pragma unroll
    for (int j=0;j<16;j++){ red[wid][j]=ss[j]; red[wid][16+j]=qq[j]; }
  }
  __syncthreads();
  if (threadIdx.x < 16){
    int j = threadIdx.x;
    float a = red[0][j]+red[1][j]+red[2][j]+red[3][j];
    float c = red[0][16+j]+red[1][16+j]+red[2][16+j]+red[3][16+j];
    float* sp = &statOut[((size_t)b*16 + j)*2];
    atomicAdd(sp, a); atomicAdd(sp+1, c);
  }
}

// ---------------- conv_out: 16->3, 7x7 reflect, tanh, PX=8; normalizes input ----------------
__global__ __launch_bounds__(256) void conv7_out_t(const float* __restrict__ in,
    const float* __restrict__ w, const float* __restrict__ bias, float* __restrict__ out,
    const float* __restrict__ statIn){
  const int H=512, W=512;
  __shared__ float wsm[16*49*3];
  __shared__ float bsm[3];
  __shared__ float msm[16], ism[16];
  for (int t=threadIdx.x; t<2352; t+=256){
    int j = t % 3; int r = t / 3;
    wsm[t] = w[j*784 + r];
  }
  if (threadIdx.x < 3) bsm[threadIdx.x] = bias[threadIdx.x];
  int idx = blockIdx.x*256 + threadIdx.x;
  int xq = idx & 63; int y = (idx >> 6) & 511; int b = idx >> 15;
  if (threadIdx.x < 16){
    const float invHW = 1.f/(512.f*512.f);
    float s  = statIn[((size_t)b*16 + threadIdx.x)*2];
    float s2 = statIn[((size_t)b*16 + threadIdx.x)*2+1];
    float m = s*invHW;
    float v = fmaxf(s2*invHW - m*m, 0.f);
    msm[threadIdx.x] = m; ism[threadIdx.x] = rsqrtf(v + EPS);
  }
  __syncthreads();
  int x0 = xq*8;
  bool colInt = (xq >= 1) && (xq <= 62);
  int ry[7];
  #pragma unroll
  for (int k=0;k<7;k++) ry[k]=refl(y+k-3,H);
  float acc[3][8];
  #pragma unroll
  for (int j=0;j<3;j++){ float bv=bsm[j];
    #pragma unroll
    for (int p=0;p<8;p++) acc[j][p]=bv; }
  const float* inb = in + (size_t)b*16*H*W;

  auto run = [&](auto INTC){
    constexpr bool INT = decltype(INTC)::value;
    int rx[14];
    if constexpr (!INT){
      #pragma unroll
      for (int q=0;q<14;q++) rx[q]=refl(x0+q-3,W);
    }
    for (int ci=0; ci<16; ++ci){
      const float* ipc = inb + (size_t)ci*H*W;
      float m = msm[ci], is = ism[ci];
      #pragma unroll
      for (int ky=0; ky<7; ++ky){
        const float* row = ipc + ry[ky]*W;
        float rv[14];
        if constexpr (INT){
          rv[0] = row[x0-3];
          float2 a = *(const float2*)(row + x0-2);
          float4 c = *(const float4*)(row + x0);
          float4 d = *(const float4*)(row + x0+4);
          float2 e = *(const float2*)(row + x0+8);
          rv[1]=a.x; rv[2]=a.y;
          rv[3]=c.x; rv[4]=c.y; rv[5]=c.z; rv[6]=c.w;
          rv[7]=d.x; rv[8]=d.y; rv[9]=d.z; rv[10]=d.w;
          rv[11]=e.x; rv[12]=e.y;
          rv[13] = row[x0+10];
        } else {
          #pragma unroll
          for (int q=0;q<14;q++) rv[q] = row[rx[q]];
        }
        #pragma unroll
        for (int q=0;q<14;q++) rv[q] = fmaxf((rv[q]-m)*is, 0.f);
        #pragma unroll
        for (int kx=0; kx<7; ++kx){
          const float* wp = &wsm[(ci*49+ky*7+kx)*3];
          float w0=wp[0], w1=wp[1], w2=wp[2];
          #pragma unroll
          for (int p=0;p<8;p++){
            float iv = rv[kx+p];
            acc[0][p] = fmaf(iv, w0, acc[0][p]);
            acc[1][p] = fmaf(iv, w1, acc[1][p]);
            acc[2][p] = fmaf(iv, w2, acc[2][p]);
          }
        }
      }
    }
  };
  if (colInt) run(std::true_type{}); else run(std::false_type{});

  float* ob = out + ((size_t)(b*3)*H + y)*W + x0;
  #pragma unroll
  for (int j=0;j<3;j++){
    float4 v0 = {tanhf(acc[j][0]),tanhf(acc[j][1]),tanhf(acc[j][2]),tanhf(acc[j][3])};
    float4 v1 = {tanhf(acc[j][4]),tanhf(acc[j][5]),tanhf(acc[j][6]),tanhf(acc[j][7])};
    *(float4*)(ob + (size_t)j*H*W)     = v0;
    *(float4*)(ob + (size_t)j*H*W + 4) = v1;
  }
}

// ---------------- 3x3 stride-2 conv, pad 1; normalizes input, emits stats ----------------
// Scalar (s_load) weights via wave-uniform index; optional 2-deep ci software pipeline.
// PIPE only safe when rv buffer small (PX=2); PIPE+PX=4 spills (R12: 890MB FETCH).
template<int CIN, int COT, int PX, bool PIPE>
__global__ __launch_bounds__(256,4) void conv3s2_t(const float* __restrict__ in,
    const float* __restrict__ w, const float* __restrict__ bias, float* __restrict__ out,
    int Hin, int Win, const float* __restrict__ statIn, float* __restrict__ statOut){
  const int Cout = 2*CIN;
  __shared__ float msm[CIN], ism[CIN];
  __shared__ float red[4][2*COT];
  int Hout = Hin>>1, Wout = Win>>1, WQ = Wout/PX;
  int idx = blockIdx.x*256 + threadIdx.x;
  int xq = idx % WQ; int t = idx / WQ;
  int y  = t % Hout;  t /= Hout;
  int cot = t % (Cout/COT); int b = t / (Cout/COT);
  int co0 = __builtin_amdgcn_readfirstlane(cot) * COT;   // wave-uniform
  {
    float invHW = 1.f/(float)(Hin*Win);
    for (int t2=threadIdx.x; t2<CIN; t2+=256){
      float s  = statIn[((size_t)b*CIN + t2)*2];
      float s2 = statIn[((size_t)b*CIN + t2)*2+1];
      float m = s*invHW;
      float v = fmaxf(s2*invHW - m*m, 0.f);
      msm[t2] = m; ism[t2] = rsqrtf(v + EPS);
    }
  }
  __syncthreads();
  int x0 = xq*PX; int ix0 = 2*x0-1; int iy0 = 2*y-1;
  bool colInt = (xq >= 1);
  float acc[COT][PX];
  #pragma unroll
  for (int j=0;j<COT;j++){ float bv = bias[co0+j];
    #pragma unroll
    for (int p=0;p<PX;p++) acc[j][p]=bv; }
  const float* inb = in + (size_t)b*CIN*Hin*Win;

  auto loadci = [&](int ci, float (&rv)[3][2*PX+1]){
    const float* ip = inb + (size_t)ci*Hin*Win;
    float m = msm[ci], is = ism[ci];
    #pragma unroll
    for (int ky=0;ky<3;ky++){
      int iy = iy0+ky;
      bool okY = (unsigned)iy < (unsigned)Hin;
      const float* row = ip + iy*Win;
      if (okY && colInt){
        rv[ky][0] = row[ix0];
        if constexpr (PX>=2){
          float4 a = *(const float4*)(row + ix0+1);
          rv[ky][1]=a.x; rv[ky][2]=a.y; rv[ky][3]=a.z; rv[ky][4]=a.w;
        } else {
          float2 a = *(const float2*)(row + ix0+1);
          rv[ky][1]=a.x; rv[ky][2]=a.y;
        }
        if constexpr (PX==4){
          float4 b4 = *(const float4*)(row + ix0+5);
          rv[ky][5]=b4.x; rv[ky][6]=b4.y; rv[ky][7]=b4.z; rv[ky][8]=b4.w;
        }
        #pragma unroll
        for (int q=0;q<2*PX+1;q++) rv[ky][q] = fmaxf((rv[ky][q]-m)*is, 0.f);
      } else {
        #pragma unroll
        for (int q=0;q<2*PX+1;q++){
          int ix = ix0+q;
          rv[ky][q] = (okY && (unsigned)ix<(unsigned)Win) ? fmaxf((row[ix]-m)*is,0.f) : 0.f;
        }
      }
    }
  };
  auto compci = [&](int ci, float (&rv)[3][2*PX+1]){
    #pragma unroll
    for (int j=0;j<COT;j++){
      const float* wj = w + ((size_t)(co0+j)*CIN + ci)*9;   // uniform -> s_load
      float wk[9];
      #pragma unroll
      for (int k=0;k<9;k++) wk[k] = wj[k];
      #pragma unroll
      for (int p=0;p<PX;p++)
        #pragma unroll
        for (int ky=0;ky<3;ky++)
          #pragma unroll
          for (int kx=0;kx<3;kx++)
            acc[j][p] = fmaf(rv[ky][2*p+kx], wk[ky*3+kx], acc[j][p]);
    }
  };

  if constexpr (PIPE){
    float rvA[3][2*PX+1], rvB[3][2*PX+1];
    loadci(0, rvA);
    for (int ci=0; ci<CIN; ci+=2){
      loadci(ci+1, rvB);
      compci(ci, rvA);
      if (ci+2 < CIN) loadci(ci+2, rvA);
      compci(ci+1, rvB);
    }
  } else {
    for (int ci=0; ci<CIN; ++ci){
      float rv[3][2*PX+1];
      loadci(ci, rv);
      compci(ci, rv);
    }
  }

  float* ob = out + (((size_t)b*Cout + co0)*Hout + y)*Wout + x0;
  #pragma unroll
  for (int j=0;j<COT;j++){
    if constexpr (PX==4){
      float4 v = {acc[j][0],acc[j][1],acc[j][2],acc[j][3]};
      *(float4*)(ob + (size_t)j*Hout*Wout) = v;
    } else if constexpr (PX==2){
      float2 v = {acc[j][0],acc[j][1]};
      *(float2*)(ob + (size_t)j*Hout*Wout) = v;
    } else {
      ob[(size_t)j*Hout*Wout] = acc[j][0];
    }
  }
  // ---- stats ----
  float ss[COT], qq[COT];
  #pragma unroll
  for (int j=0;j<COT;j++){
    float a=0.f,c=0.f;
    #pragma unroll
    for (int p=0;p<PX;p++){ a+=acc[j][p]; c=fmaf(acc[j][p],acc[j][p],c); }
    ss[j]=a; qq[j]=c;
  }
  #pragma unroll
  for (int o=32;o>0;o>>=1){
    #pragma unroll
    for (int j=0;j<COT;j++){ ss[j]+=__shfl_down(ss[j],o); qq[j]+=__shfl_down(qq[j],o); }
  }
  int lane = threadIdx.x & 63, wid = threadIdx.x >> 6;
  if (lane==0){
    #pragma unroll
    for (int j=0;j<COT;j++){ red[wid][j]=ss[j]; red[wid][COT+j]=qq[j]; }
  }
  __syncthreads();
  if (threadIdx.x < COT){
    int j = threadIdx.x;
    float a = red[0][j]+red[1][j]+red[2][j]+red[3][j];
    float c = red[0][COT+j]+red[1][COT+j]+red[2][COT+j]+red[3][COT+j];
    float* sp = &statOut[((size_t)b*Cout + co0 + j)*2];
    atomicAdd(sp, a); atomicAdd(sp+1, c);
  }
}

// ---------------- tconv k=3 s=2 p=1 op=1; scalar weights; 2-deep ci pipeline ----------------
template<int CIN, int COT>
__global__ __launch_bounds__(256,4) void tconv3_t(const float* __restrict__ in,
    const float* __restrict__ w, const float* __restrict__ bias, float* __restrict__ out,
    int Hin, int Win, const float* __restrict__ statIn, float* __restrict__ statOut){
  const int PX=2, Cout = CIN/2;
  __shared__ float msm[CIN], ism[CIN];
  __shared__ float red[4][2*COT];
  int Hout = Hin*2, Wout = Win*2, WQ = Win/PX;
  int idx = blockIdx.x*256 + threadIdx.x;
  int xq = idx % WQ; int t = idx / WQ;
  int yo = t % Hin;  t /= Hin;
  int cot = t % (Cout/COT); int b = t / (Cout/COT);
  int co0 = __builtin_amdgcn_readfirstlane(cot) * COT;  // wave-uniform
  {
    float invHW = 1.f/(float)(Hin*Win);
    for (int t2=threadIdx.x; t2<CIN; t2+=256){
      float s  = statIn[((size_t)b*CIN + t2)*2];
      float s2 = statIn[((size_t)b*CIN + t2)*2+1];
      float m = s*invHW;
      float v = fmaxf(s2*invHW - m*m, 0.f);
      msm[t2] = m; ism[t2] = rsqrtf(v + EPS);
    }
  }
  __syncthreads();
  int xo0 = xq*PX;
  bool okY1 = (yo+1) < Hin;
  bool fast = okY1 && (xo0+2 < Win);
  float acc[COT][2][2*PX];
  #pragma unroll
  for (int j=0;j<COT;j++){ float bv = bias[co0+j];
    #pragma unroll
    for (int oy=0;oy<2;oy++)
      #pragma unroll
      for (int ox=0;ox<2*PX;ox++) acc[j][oy][ox]=bv; }
  const float* inb = in + (size_t)b*CIN*Hin*Win;

  auto loadci = [&](int ci, float (&v)[2][PX+1]){
    const float* ip = inb + (size_t)ci*Hin*Win + (size_t)yo*Win;
    float m = msm[ci], is = ism[ci];
    if (fast){
      float2 a = *(const float2*)(ip + xo0);
      float2 b2 = *(const float2*)(ip + Win + xo0);
      v[0][0]=a.x;  v[0][1]=a.y;  v[0][2]=ip[xo0+2];
      v[1][0]=b2.x; v[1][1]=b2.y; v[1][2]=ip[Win+xo0+2];
      #pragma unroll
      for (int r=0;r<2;r++)
        #pragma unroll
        for (int c=0;c<3;c++) v[r][c] = fmaxf((v[r][c]-m)*is, 0.f);
    } else {
      #pragma unroll
      for (int c=0;c<PX+1;c++){
        int xc = xo0+c; bool okX = xc < Win;
        v[0][c] = okX ? fmaxf((ip[xc]-m)*is,0.f) : 0.f;
        v[1][c] = (okX && okY1) ? fmaxf((ip[Win+xc]-m)*is,0.f) : 0.f;
      }
    }
  };
  auto compci = [&](int ci, float (&v)[2][PX+1]){
    #pragma unroll
    for (int j=0;j<COT;j++){
      const float* wj = w + ((size_t)ci*Cout + co0+j)*9;   // uniform -> s_load
      float wk[9];
      #pragma unroll
      for (int k=0;k<9;k++) wk[k] = wj[k];
      #pragma unroll
      for (int q=0;q<PX;q++){
        float v00=v[0][q], v01=v[0][q+1], v10=v[1][q], v11=v[1][q+1];
        acc[j][0][2*q]   = fmaf(v00, wk[4], acc[j][0][2*q]);
        acc[j][0][2*q+1] = fmaf(v00, wk[5], fmaf(v01, wk[3], acc[j][0][2*q+1]));
        acc[j][1][2*q]   = fmaf(v00, wk[7], fmaf(v10, wk[1], acc[j][1][2*q]));
        acc[j][1][2*q+1] = fmaf(v00, wk[8], fmaf(v01, wk[6],
                           fmaf(v10, wk[2], fmaf(v11, wk[0], acc[j][1][2*q+1]))));
      }
    }
  };

  float vA[2][PX+1], vB[2][PX+1];
  loadci(0, vA);
  for (int ci=0; ci<CIN; ci+=2){
    loadci(ci+1, vB);
    compci(ci, vA);
    if (ci+2 < CIN) loadci(ci+2, vA);
    compci(ci+1, vB);
  }

  float* ob = out + (((size_t)b*Cout + co0)*Hout + 2*yo)*Wout + 2*xo0;
  #pragma unroll
  for (int j=0;j<COT;j++){
    float4 r0 = {acc[j][0][0],acc[j][0][1],acc[j][0][2],acc[j][0][3]};
    float4 r1 = {acc[j][1][0],acc[j][1][1],acc[j][1][2],acc[j][1][3]};
    *(float4*)(ob + (size_t)j*Hout*Wout)        = r0;
    *(float4*)(ob + (size_t)j*Hout*Wout + Wout) = r1;
  }
  // ---- stats ----
  float ss[COT], qq[COT];
  #pragma unroll
  for (int j=0;j<COT;j++){
    float a=0.f,c=0.f;
    #pragma unroll
    for (int oy=0;oy<2;oy++)
      #pragma unroll
      for (int ox=0;ox<2*PX;ox++){ float u=acc[j][oy][ox]; a+=u; c=fmaf(u,u,c); }
    ss[j]=a; qq[j]=c;
  }
  #pragma unroll
  for (int o=32;o>0;o>>=1){
    #pragma unroll
    for (int j=0;j<COT;j++){ ss[j]+=__shfl_down(ss[j],o); qq[j]+=__shfl_down(qq[j],o); }
  }
  int lane = threadIdx.x & 63, wid = threadIdx.x >> 6;
  if (lane==0){
    #pragma unroll
    for (int j=0;j<COT;j++){ red[wid][j]=ss[j]; red[wid][COT+j]=qq[j]; }
  }
  __syncthreads();
  if (threadIdx.x < COT){
    int j = threadIdx.x;
    float a = red[0][j]+red[1][j]+red[2][j]+red[3][j];
    float c = red[0][COT+j]+red[1][COT+j]+red[2][COT+j]+red[3][COT+j];
    float* sp = &statOut[((size_t)b*Cout + co0 + j)*2];
    atomicAdd(sp, a); atomicAdd(sp+1, c);
  }
}

// ---------------- per-(b,id) scatter-mean: accumulate ----------------
__global__ void pool_accum(const float* __restrict__ t, const int* __restrict__ imap,
                           float* __restrict__ sums, float* __restrict__ cnts){
  const int P = 512*512;
  int b = blockIdx.y;
  __shared__ float ls[96];
  __shared__ float lc[32];
  for (int i=threadIdx.x;i<96;i+=blockDim.x) ls[i]=0.f;
  if (threadIdx.x<32) lc[threadIdx.x]=0.f;
  __syncthreads();
  const float* tb = t + (size_t)b*3*P;
  const int*   mb = imap + (size_t)b*P;
  for (int p = blockIdx.x*blockDim.x + threadIdx.x; p < P; p += gridDim.x*blockDim.x){
    int id = mb[p];
    atomicAdd(&ls[id*3+0], tb[p]);
    atomicAdd(&ls[id*3+1], tb[P+p]);
    atomicAdd(&ls[id*3+2], tb[2*P+p]);
    atomicAdd(&lc[id], 1.0f);
  }
  __syncthreads();
  for (int i=threadIdx.x;i<96;i+=blockDim.x) atomicAdd(&sums[b*96+i], ls[i]);
  if (threadIdx.x<32) atomicAdd(&cnts[b*32+threadIdx.x], lc[threadIdx.x]);
}

// ---------------- broadcast means back ----------------
__global__ void pool_bcast(float* __restrict__ out, const int* __restrict__ imap,
                           const float* __restrict__ sums, const float* __restrict__ cnts){
  const int P = 512*512;
  int b = blockIdx.y;
  __shared__ float lm[96];
  if (threadIdx.x < 96){
    int id = threadIdx.x/3;
    lm[threadIdx.x] = sums[b*96+threadIdx.x] / fmaxf(cnts[b*32+id], 1.0f);
  }
  __syncthreads();
  const int* mb = imap + (size_t)b*P;
  float* ob = out + (size_t)b*3*P;
  for (int p = blockIdx.x*blockDim.x + threadIdx.x; p < P; p += gridDim.x*blockDim.x){
    int id = mb[p];
    ob[p]     = lm[id*3+0];
    ob[P+p]   = lm[id*3+1];
    ob[2*P+p] = lm[id*3+2];
  }
}

static inline int cdiv(int a, int b){ return (a+b-1)/b; }

extern "C" void kernel_launch(void* const* d_in, const int* in_sizes, int n_in,
                              void* d_out, int out_size, void* d_ws, size_t ws_size,
                              hipStream_t stream) {
  const float* x    = (const float*)d_in[0];
  const int*   imap = (const int*)d_in[1];
  const float* w_in = (const float*)d_in[2];
  const float* b_in = (const float*)d_in[3];
  const float *wd[4], *bd[4], *wu[4], *bu[4];
  for (int i=0;i<4;i++){ wd[i]=(const float*)d_in[4+2*i];  bd[i]=(const float*)d_in[5+2*i]; }
  for (int i=0;i<4;i++){ wu[i]=(const float*)d_in[12+2*i]; bu[i]=(const float*)d_in[13+2*i]; }
  const float* w_out = (const float*)d_in[20];
  const float* b_out = (const float*)d_in[21];
  float* out = (float*)d_out;

  char* ws = (char*)d_ws;
  float* A     = (float*)ws;
  float* Bb    = (float*)(ws + (size_t)134217728);
  float* stats = (float*)(ws + (size_t)134217728 + (size_t)67108864);
  float* stLin = stats;          // 8*16*2  = 256
  float* std0  = stLin + 256;    // 8*32*2  = 512
  float* std1  = std0  + 512;    // 8*64*2  = 1024
  float* std2  = std1  + 1024;   // 8*128*2 = 2048
  float* std3  = std2  + 2048;   // 8*256*2 = 4096
  float* stu0  = std3  + 4096;   // 8*128*2 = 2048
  float* stu1  = stu0  + 2048;   // 8*64*2  = 1024
  float* stu2  = stu1  + 1024;   // 8*32*2  = 512
  float* stu3  = stu2  + 512;    // 8*16*2  = 256
  float* sums  = stu3  + 256;    // [8][32][3] = 768
  float* cnts  = sums  + 768;    // [8][32]    = 256
  hipMemsetAsync(stats, 0, (size_t)(11776 + 1024)*sizeof(float), stream);

  // conv_in: 3 -> 16 @ 512x512 (raw input, emits stLin)
  conv7_in_t<<<2048, 256, 0, stream>>>(x, w_in, b_in, A, stLin);

  // down path (normalize input via statIn, emit statOut)
  conv3s2_t<16,8,4,false><<<2048, 256, 0, stream>>>(A,  wd[0], bd[0], Bb, 512, 512, stLin, std0);
  conv3s2_t<32,8,4,false><<<1024, 256, 0, stream>>>(Bb, wd[1], bd[1], A,  256, 256, std0, std1);
  conv3s2_t<64,4,4,false><<<1024, 256, 0, stream>>>(A,  wd[2], bd[2], Bb, 128, 128, std1, std2);
  conv3s2_t<128,2,4,false><<<1024, 256, 0, stream>>>(Bb, wd[3], bd[3], A,  64,  64, std2, std3);

  // up path (R10 configs)
  tconv3_t<256,2><<<1024, 256, 0, stream>>>(A,  wu[0], bu[0], Bb, 32, 32, std3, stu0);
  tconv3_t<128,4><<<1024, 256, 0, stream>>>(Bb, wu[1], bu[1], A,  64, 64, stu0, stu1);
  tconv3_t<64,8><<<1024, 256, 0, stream>>>(A,  wu[2], bu[2], Bb, 128, 128, stu1, stu2);
  tconv3_t<32,8><<<2048, 256, 0, stream>>>(Bb, wu[3], bu[3], A,  256, 256, stu2, stu3);

  // conv_out: 16 -> 3 @ 512x512 + tanh (normalizes u3 on load)
  conv7_out_t<<<1024, 256, 0, stream>>>(A, w_out, b_out, out, stu3);

  // scatter-mean pooling over instance ids
  pool_accum<<<dim3(64,BATCH),256,0,stream>>>(out, imap, sums, cnts);
  pool_bcast<<<dim3(128,BATCH),256,0,stream>>>(out, imap, sums, cnts);
}

// Round 14
// 2350.512 us; speedup vs baseline: 1.5213x; 1.1367x over previous
//
#include <hip/hip_runtime.h>
#include <math.h>
#include <type_traits>

#define BATCH 8
#define EPS 1e-5f

__device__ __forceinline__ int refl(int p, int n){ return p<0 ? -p : (p>=n ? 2*n-2-p : p); }

// stat layout per layer: stat[(b*C + c)*2] = sum, +1 = sumsq (atomic-accumulated)

// ---------------- conv_in: 3->16, 7x7, reflect pad 3, 512x512, COT=16, PX=4 ----------------
__global__ __launch_bounds__(256) void conv7_in_t(const float* __restrict__ in,
    const float* __restrict__ w, const float* __restrict__ bias, float* __restrict__ out,
    float* __restrict__ statOut){
  const int H=512, W=512;
  __shared__ float wsm[3*49*16];
  __shared__ float bsm[16];
  __shared__ float red[4][32];
  for (int t=threadIdx.x; t<2352; t+=256){
    int j = t & 15; int r = t >> 4;
    wsm[t] = w[j*147 + r];
  }
  if (threadIdx.x < 16) bsm[threadIdx.x] = bias[threadIdx.x];
  __syncthreads();
  int idx = blockIdx.x*256 + threadIdx.x;
  int xq = idx & 127; int y = (idx >> 7) & 511; int b = idx >> 16;
  int x0 = xq*4;
  bool colInt = (xq >= 1) && (xq <= 126);
  int ry[7];
  #pragma unroll
  for (int k=0;k<7;k++) ry[k]=refl(y+k-3,H);
  float acc[16][4];
  #pragma unroll
  for (int j=0;j<16;j++){ float bv=bsm[j];
    #pragma unroll
    for (int p=0;p<4;p++) acc[j][p]=bv; }
  const float* inb = in + (size_t)b*3*H*W;

  auto run = [&](auto INTC){
    constexpr bool INT = decltype(INTC)::value;
    int rx[10];
    if constexpr (!INT){
      #pragma unroll
      for (int q=0;q<10;q++) rx[q]=refl(x0+q-3,W);
    }
    for (int ci=0; ci<3; ++ci){
      const float* ipc = inb + ci*H*W;
      #pragma unroll
      for (int ky=0; ky<7; ++ky){
        const float* row = ipc + ry[ky]*W;
        float rv[10];
        if constexpr (INT){
          rv[0] = row[x0-3];
          float2 a = *(const float2*)(row + x0-2);
          float4 c = *(const float4*)(row + x0);
          float2 d = *(const float2*)(row + x0+4);
          rv[1]=a.x; rv[2]=a.y;
          rv[3]=c.x; rv[4]=c.y; rv[5]=c.z; rv[6]=c.w;
          rv[7]=d.x; rv[8]=d.y;
          rv[9] = row[x0+6];
        } else {
          #pragma unroll
          for (int q=0;q<10;q++) rv[q] = row[rx[q]];
        }
        #pragma unroll
        for (int kx=0; kx<7; ++kx){
          const float4* wp = (const float4*)&wsm[(ci*49+ky*7+kx)*16];
          float4 w0=wp[0], w1=wp[1], w2=wp[2], w3=wp[3];
          float wv[16] = {w0.x,w0.y,w0.z,w0.w, w1.x,w1.y,w1.z,w1.w,
                          w2.x,w2.y,w2.z,w2.w, w3.x,w3.y,w3.z,w3.w};
          #pragma unroll
          for (int p=0;p<4;p++){
            float iv = rv[kx+p];
            #pragma unroll
            for (int j=0;j<16;j++) acc[j][p] = fmaf(iv, wv[j], acc[j][p]);
          }
        }
      }
    }
  };
  if (colInt) run(std::true_type{}); else run(std::false_type{});

  float* ob = out + ((size_t)(b*16)*H + y)*W + x0;
  #pragma unroll
  for (int j=0;j<16;j++){
    float4 v = {acc[j][0],acc[j][1],acc[j][2],acc[j][3]};
    *(float4*)(ob + (size_t)j*H*W) = v;
  }
  // ---- stats ----
  float ss[16], qq[16];
  #pragma unroll
  for (int j=0;j<16;j++){
    float a=0.f,c=0.f;
    #pragma unroll
    for (int p=0;p<4;p++){ a+=acc[j][p]; c=fmaf(acc[j][p],acc[j][p],c); }
    ss[j]=a; qq[j]=c;
  }
  #pragma unroll
  for (int o=32;o>0;o>>=1){
    #pragma unroll
    for (int j=0;j<16;j++){ ss[j]+=__shfl_down(ss[j],o); qq[j]+=__shfl_down(qq[j],o); }
  }
  int lane = threadIdx.x & 63, wid = threadIdx.x >> 6;
  if (lane==0){
    #pragma unroll
    for (int j=0;j<16;j++){ red[wid][j]=ss[j]; red[wid][16+j]=qq[j]; }
  }
  __syncthreads();
  if (threadIdx.x < 16){
    int j = threadIdx.x;
    float a = red[0][j]+red[1][j]+red[2][j]+red[3][j];
    float c = red[0][16+j]+red[1][16+j]+red[2][16+j]+red[3][16+j];
    float* sp = &statOut[((size_t)b*16 + j)*2];
    atomicAdd(sp, a); atomicAdd(sp+1, c);
  }
}

// ---------------- conv_out: 16->3, 7x7 reflect, tanh, PX=8; normalizes input ----------------
// Fused per-(b,id) scatter-sum epilogue (replaces pool_accum kernel).
__global__ __launch_bounds__(256) void conv7_out_t(const float* __restrict__ in,
    const float* __restrict__ w, const float* __restrict__ bias, float* __restrict__ out,
    const float* __restrict__ statIn, const int* __restrict__ imap,
    float* __restrict__ sums, float* __restrict__ cnts){
  const int H=512, W=512;
  __shared__ float wsm[16*49*3];
  __shared__ float bsm[3];
  __shared__ float msm[16], ism[16];
  __shared__ float ls[96];
  __shared__ float lc[32];
  for (int t=threadIdx.x; t<2352; t+=256){
    int j = t % 3; int r = t / 3;
    wsm[t] = w[j*784 + r];
  }
  if (threadIdx.x < 3) bsm[threadIdx.x] = bias[threadIdx.x];
  if (threadIdx.x < 96) ls[threadIdx.x] = 0.f;
  if (threadIdx.x >= 96 && threadIdx.x < 128) lc[threadIdx.x-96] = 0.f;
  int idx = blockIdx.x*256 + threadIdx.x;
  int xq = idx & 63; int y = (idx >> 6) & 511; int b = idx >> 15;
  if (threadIdx.x < 16){
    const float invHW = 1.f/(512.f*512.f);
    float s  = statIn[((size_t)b*16 + threadIdx.x)*2];
    float s2 = statIn[((size_t)b*16 + threadIdx.x)*2+1];
    float m = s*invHW;
    float v = fmaxf(s2*invHW - m*m, 0.f);
    msm[threadIdx.x] = m; ism[threadIdx.x] = rsqrtf(v + EPS);
  }
  __syncthreads();
  int x0 = xq*8;
  bool colInt = (xq >= 1) && (xq <= 62);
  int ry[7];
  #pragma unroll
  for (int k=0;k<7;k++) ry[k]=refl(y+k-3,H);
  float acc[3][8];
  #pragma unroll
  for (int j=0;j<3;j++){ float bv=bsm[j];
    #pragma unroll
    for (int p=0;p<8;p++) acc[j][p]=bv; }
  const float* inb = in + (size_t)b*16*H*W;

  auto run = [&](auto INTC){
    constexpr bool INT = decltype(INTC)::value;
    int rx[14];
    if constexpr (!INT){
      #pragma unroll
      for (int q=0;q<14;q++) rx[q]=refl(x0+q-3,W);
    }
    for (int ci=0; ci<16; ++ci){
      const float* ipc = inb + (size_t)ci*H*W;
      float m = msm[ci], is = ism[ci];
      #pragma unroll
      for (int ky=0; ky<7; ++ky){
        const float* row = ipc + ry[ky]*W;
        float rv[14];
        if constexpr (INT){
          rv[0] = row[x0-3];
          float2 a = *(const float2*)(row + x0-2);
          float4 c = *(const float4*)(row + x0);
          float4 d = *(const float4*)(row + x0+4);
          float2 e = *(const float2*)(row + x0+8);
          rv[1]=a.x; rv[2]=a.y;
          rv[3]=c.x; rv[4]=c.y; rv[5]=c.z; rv[6]=c.w;
          rv[7]=d.x; rv[8]=d.y; rv[9]=d.z; rv[10]=d.w;
          rv[11]=e.x; rv[12]=e.y;
          rv[13] = row[x0+10];
        } else {
          #pragma unroll
          for (int q=0;q<14;q++) rv[q] = row[rx[q]];
        }
        #pragma unroll
        for (int q=0;q<14;q++) rv[q] = fmaxf((rv[q]-m)*is, 0.f);
        #pragma unroll
        for (int kx=0; kx<7; ++kx){
          const float* wp = &wsm[(ci*49+ky*7+kx)*3];
          float w0=wp[0], w1=wp[1], w2=wp[2];
          #pragma unroll
          for (int p=0;p<8;p++){
            float iv = rv[kx+p];
            acc[0][p] = fmaf(iv, w0, acc[0][p]);
            acc[1][p] = fmaf(iv, w1, acc[1][p]);
            acc[2][p] = fmaf(iv, w2, acc[2][p]);
          }
        }
      }
    }
  };
  if (colInt) run(std::true_type{}); else run(std::false_type{});

  // tanh + store
  #pragma unroll
  for (int j=0;j<3;j++)
    #pragma unroll
    for (int p=0;p<8;p++) acc[j][p] = tanhf(acc[j][p]);

  float* ob = out + ((size_t)(b*3)*H + y)*W + x0;
  #pragma unroll
  for (int j=0;j<3;j++){
    float4 v0 = {acc[j][0],acc[j][1],acc[j][2],acc[j][3]};
    float4 v1 = {acc[j][4],acc[j][5],acc[j][6],acc[j][7]};
    *(float4*)(ob + (size_t)j*H*W)     = v0;
    *(float4*)(ob + (size_t)j*H*W + 4) = v1;
  }

  // ---- fused scatter-sum pooling epilogue ----
  const int* mb = imap + ((size_t)b*H + y)*W + x0;
  int4 i0 = *(const int4*)(mb);
  int4 i1 = *(const int4*)(mb + 4);
  int im[8] = {i0.x,i0.y,i0.z,i0.w, i1.x,i1.y,i1.z,i1.w};
  #pragma unroll
  for (int p=0;p<8;p++){
    int id = im[p];
    atomicAdd(&ls[id*3+0], acc[0][p]);
    atomicAdd(&ls[id*3+1], acc[1][p]);
    atomicAdd(&ls[id*3+2], acc[2][p]);
    atomicAdd(&lc[id], 1.0f);
  }
  __syncthreads();
  if (threadIdx.x < 96) atomicAdd(&sums[b*96+threadIdx.x], ls[threadIdx.x]);
  if (threadIdx.x >= 96 && threadIdx.x < 128) atomicAdd(&cnts[b*32+threadIdx.x-96], lc[threadIdx.x-96]);
}

// ---------------- 3x3 stride-2 conv, pad 1; normalizes input, emits stats ----------------
// Scalar (s_load) weights via wave-uniform index; optional 2-deep ci software pipeline.
// PIPE only safe when rv buffer small (PX=2); PIPE+PX=4 spills (R12: 890MB FETCH).
template<int CIN, int COT, int PX, bool PIPE>
__global__ __launch_bounds__(256,4) void conv3s2_t(const float* __restrict__ in,
    const float* __restrict__ w, const float* __restrict__ bias, float* __restrict__ out,
    int Hin, int Win, const float* __restrict__ statIn, float* __restrict__ statOut){
  const int Cout = 2*CIN;
  __shared__ float msm[CIN], ism[CIN];
  __shared__ float red[4][2*COT];
  int Hout = Hin>>1, Wout = Win>>1, WQ = Wout/PX;
  int idx = blockIdx.x*256 + threadIdx.x;
  int xq = idx % WQ; int t = idx / WQ;
  int y  = t % Hout;  t /= Hout;
  int cot = t % (Cout/COT); int b = t / (Cout/COT);
  int co0 = __builtin_amdgcn_readfirstlane(cot) * COT;   // wave-uniform
  {
    float invHW = 1.f/(float)(Hin*Win);
    for (int t2=threadIdx.x; t2<CIN; t2+=256){
      float s  = statIn[((size_t)b*CIN + t2)*2];
      float s2 = statIn[((size_t)b*CIN + t2)*2+1];
      float m = s*invHW;
      float v = fmaxf(s2*invHW - m*m, 0.f);
      msm[t2] = m; ism[t2] = rsqrtf(v + EPS);
    }
  }
  __syncthreads();
  int x0 = xq*PX; int ix0 = 2*x0-1; int iy0 = 2*y-1;
  bool colInt = (xq >= 1);
  float acc[COT][PX];
  #pragma unroll
  for (int j=0;j<COT;j++){ float bv = bias[co0+j];
    #pragma unroll
    for (int p=0;p<PX;p++) acc[j][p]=bv; }
  const float* inb = in + (size_t)b*CIN*Hin*Win;

  auto loadci = [&](int ci, float (&rv)[3][2*PX+1]){
    const float* ip = inb + (size_t)ci*Hin*Win;
    float m = msm[ci], is = ism[ci];
    #pragma unroll
    for (int ky=0;ky<3;ky++){
      int iy = iy0+ky;
      bool okY = (unsigned)iy < (unsigned)Hin;
      const float* row = ip + iy*Win;
      if (okY && colInt){
        rv[ky][0] = row[ix0];
        if constexpr (PX>=2){
          float4 a = *(const float4*)(row + ix0+1);
          rv[ky][1]=a.x; rv[ky][2]=a.y; rv[ky][3]=a.z; rv[ky][4]=a.w;
        } else {
          float2 a = *(const float2*)(row + ix0+1);
          rv[ky][1]=a.x; rv[ky][2]=a.y;
        }
        if constexpr (PX==4){
          float4 b4 = *(const float4*)(row + ix0+5);
          rv[ky][5]=b4.x; rv[ky][6]=b4.y; rv[ky][7]=b4.z; rv[ky][8]=b4.w;
        }
        #pragma unroll
        for (int q=0;q<2*PX+1;q++) rv[ky][q] = fmaxf((rv[ky][q]-m)*is, 0.f);
      } else {
        #pragma unroll
        for (int q=0;q<2*PX+1;q++){
          int ix = ix0+q;
          rv[ky][q] = (okY && (unsigned)ix<(unsigned)Win) ? fmaxf((row[ix]-m)*is,0.f) : 0.f;
        }
      }
    }
  };
  auto compci = [&](int ci, float (&rv)[3][2*PX+1]){
    #pragma unroll
    for (int j=0;j<COT;j++){
      const float* wj = w + ((size_t)(co0+j)*CIN + ci)*9;   // uniform -> s_load
      float wk[9];
      #pragma unroll
      for (int k=0;k<9;k++) wk[k] = wj[k];
      #pragma unroll
      for (int p=0;p<PX;p++)
        #pragma unroll
        for (int ky=0;ky<3;ky++)
          #pragma unroll
          for (int kx=0;kx<3;kx++)
            acc[j][p] = fmaf(rv[ky][2*p+kx], wk[ky*3+kx], acc[j][p]);
    }
  };

  if constexpr (PIPE){
    float rvA[3][2*PX+1], rvB[3][2*PX+1];
    loadci(0, rvA);
    for (int ci=0; ci<CIN; ci+=2){
      loadci(ci+1, rvB);
      compci(ci, rvA);
      if (ci+2 < CIN) loadci(ci+2, rvA);
      compci(ci+1, rvB);
    }
  } else {
    for (int ci=0; ci<CIN; ++ci){
      float rv[3][2*PX+1];
      loadci(ci, rv);
      compci(ci, rv);
    }
  }

  float* ob = out + (((size_t)b*Cout + co0)*Hout + y)*Wout + x0;
  #pragma unroll
  for (int j=0;j<COT;j++){
    if constexpr (PX==4){
      float4 v = {acc[j][0],acc[j][1],acc[j][2],acc[j][3]};
      *(float4*)(ob + (size_t)j*Hout*Wout) = v;
    } else if constexpr (PX==2){
      float2 v = {acc[j][0],acc[j][1]};
      *(float2*)(ob + (size_t)j*Hout*Wout) = v;
    } else {
      ob[(size_t)j*Hout*Wout] = acc[j][0];
    }
  }
  // ---- stats ----
  float ss[COT], qq[COT];
  #pragma unroll
  for (int j=0;j<COT;j++){
    float a=0.f,c=0.f;
    #pragma unroll
    for (int p=0;p<PX;p++){ a+=acc[j][p]; c=fmaf(acc[j][p],acc[j][p],c); }
    ss[j]=a; qq[j]=c;
  }
  #pragma unroll
  for (int o=32;o>0;o>>=1){
    #pragma unroll
    for (int j=0;j<COT;j++){ ss[j]+=__shfl_down(ss[j],o); qq[j]+=__shfl_down(qq[j],o); }
  }
  int lane = threadIdx.x & 63, wid = threadIdx.x >> 6;
  if (lane==0){
    #pragma unroll
    for (int j=0;j<COT;j++){ red[wid][j]=ss[j]; red[wid][COT+j]=qq[j]; }
  }
  __syncthreads();
  if (threadIdx.x < COT){
    int j = threadIdx.x;
    float a = red[0][j]+red[1][j]+red[2][j]+red[3][j];
    float c = red[0][COT+j]+red[1][COT+j]+red[2][COT+j]+red[3][COT+j];
    float* sp = &statOut[((size_t)b*Cout + co0 + j)*2];
    atomicAdd(sp, a); atomicAdd(sp+1, c);
  }
}

// ---------------- tconv k=3 s=2 p=1 op=1; scalar weights; 2-deep ci pipeline ----------------
template<int CIN, int COT>
__global__ __launch_bounds__(256,4) void tconv3_t(const float* __restrict__ in,
    const float* __restrict__ w, const float* __restrict__ bias, float* __restrict__ out,
    int Hin, int Win, const float* __restrict__ statIn, float* __restrict__ statOut){
  const int PX=2, Cout = CIN/2;
  __shared__ float msm[CIN], ism[CIN];
  __shared__ float red[4][2*COT];
  int Hout = Hin*2, Wout = Win*2, WQ = Win/PX;
  int idx = blockIdx.x*256 + threadIdx.x;
  int xq = idx % WQ; int t = idx / WQ;
  int yo = t % Hin;  t /= Hin;
  int cot = t % (Cout/COT); int b = t / (Cout/COT);
  int co0 = __builtin_amdgcn_readfirstlane(cot) * COT;  // wave-uniform
  {
    float invHW = 1.f/(float)(Hin*Win);
    for (int t2=threadIdx.x; t2<CIN; t2+=256){
      float s  = statIn[((size_t)b*CIN + t2)*2];
      float s2 = statIn[((size_t)b*CIN + t2)*2+1];
      float m = s*invHW;
      float v = fmaxf(s2*invHW - m*m, 0.f);
      msm[t2] = m; ism[t2] = rsqrtf(v + EPS);
    }
  }
  __syncthreads();
  int xo0 = xq*PX;
  bool okY1 = (yo+1) < Hin;
  bool fast = okY1 && (xo0+2 < Win);
  float acc[COT][2][2*PX];
  #pragma unroll
  for (int j=0;j<COT;j++){ float bv = bias[co0+j];
    #pragma unroll
    for (int oy=0;oy<2;oy++)
      #pragma unroll
      for (int ox=0;ox<2*PX;ox++) acc[j][oy][ox]=bv; }
  const float* inb = in + (size_t)b*CIN*Hin*Win;

  auto loadci = [&](int ci, float (&v)[2][PX+1]){
    const float* ip = inb + (size_t)ci*Hin*Win + (size_t)yo*Win;
    float m = msm[ci], is = ism[ci];
    if (fast){
      float2 a = *(const float2*)(ip + xo0);
      float2 b2 = *(const float2*)(ip + Win + xo0);
      v[0][0]=a.x;  v[0][1]=a.y;  v[0][2]=ip[xo0+2];
      v[1][0]=b2.x; v[1][1]=b2.y; v[1][2]=ip[Win+xo0+2];
      #pragma unroll
      for (int r=0;r<2;r++)
        #pragma unroll
        for (int c=0;c<3;c++) v[r][c] = fmaxf((v[r][c]-m)*is, 0.f);
    } else {
      #pragma unroll
      for (int c=0;c<PX+1;c++){
        int xc = xo0+c; bool okX = xc < Win;
        v[0][c] = okX ? fmaxf((ip[xc]-m)*is,0.f) : 0.f;
        v[1][c] = (okX && okY1) ? fmaxf((ip[Win+xc]-m)*is,0.f) : 0.f;
      }
    }
  };
  auto compci = [&](int ci, float (&v)[2][PX+1]){
    #pragma unroll
    for (int j=0;j<COT;j++){
      const float* wj = w + ((size_t)ci*Cout + co0+j)*9;   // uniform -> s_load
      float wk[9];
      #pragma unroll
      for (int k=0;k<9;k++) wk[k] = wj[k];
      #pragma unroll
      for (int q=0;q<PX;q++){
        float v00=v[0][q], v01=v[0][q+1], v10=v[1][q], v11=v[1][q+1];
        acc[j][0][2*q]   = fmaf(v00, wk[4], acc[j][0][2*q]);
        acc[j][0][2*q+1] = fmaf(v00, wk[5], fmaf(v01, wk[3], acc[j][0][2*q+1]));
        acc[j][1][2*q]   = fmaf(v00, wk[7], fmaf(v10, wk[1], acc[j][1][2*q]));
        acc[j][1][2*q+1] = fmaf(v00, wk[8], fmaf(v01, wk[6],
                           fmaf(v10, wk[2], fmaf(v11, wk[0], acc[j][1][2*q+1]))));
      }
    }
  };

  float vA[2][PX+1], vB[2][PX+1];
  loadci(0, vA);
  for (int ci=0; ci<CIN; ci+=2){
    loadci(ci+1, vB);
    compci(ci, vA);
    if (ci+2 < CIN) loadci(ci+2, vA);
    compci(ci+1, vB);
  }

  float* ob = out + (((size_t)b*Cout + co0)*Hout + 2*yo)*Wout + 2*xo0;
  #pragma unroll
  for (int j=0;j<COT;j++){
    float4 r0 = {acc[j][0][0],acc[j][0][1],acc[j][0][2],acc[j][0][3]};
    float4 r1 = {acc[j][1][0],acc[j][1][1],acc[j][1][2],acc[j][1][3]};
    *(float4*)(ob + (size_t)j*Hout*Wout)        = r0;
    *(float4*)(ob + (size_t)j*Hout*Wout + Wout) = r1;
  }
  // ---- stats ----
  float ss[COT], qq[COT];
  #pragma unroll
  for (int j=0;j<COT;j++){
    float a=0.f,c=0.f;
    #pragma unroll
    for (int oy=0;oy<2;oy++)
      #pragma unroll
      for (int ox=0;ox<2*PX;ox++){ float u=acc[j][oy][ox]; a+=u; c=fmaf(u,u,c); }
    ss[j]=a; qq[j]=c;
  }
  #pragma unroll
  for (int o=32;o>0;o>>=1){
    #pragma unroll
    for (int j=0;j<COT;j++){ ss[j]+=__shfl_down(ss[j],o); qq[j]+=__shfl_down(qq[j],o); }
  }
  int lane = threadIdx.x & 63, wid = threadIdx.x >> 6;
  if (lane==0){
    #pragma unroll
    for (int j=0;j<COT;j++){ red[wid][j]=ss[j]; red[wid][COT+j]=qq[j]; }
  }
  __syncthreads();
  if (threadIdx.x < COT){
    int j = threadIdx.x;
    float a = red[0][j]+red[1][j]+red[2][j]+red[3][j];
    float c = red[0][COT+j]+red[1][COT+j]+red[2][COT+j]+red[3][COT+j];
    float* sp = &statOut[((size_t)b*Cout + co0 + j)*2];
    atomicAdd(sp, a); atomicAdd(sp+1, c);
  }
}

// ---------------- broadcast means back ----------------
__global__ void pool_bcast(float* __restrict__ out, const int* __restrict__ imap,
                           const float* __restrict__ sums, const float* __restrict__ cnts){
  const int P = 512*512;
  int b = blockIdx.y;
  __shared__ float lm[96];
  if (threadIdx.x < 96){
    int id = threadIdx.x/3;
    lm[threadIdx.x] = sums[b*96+threadIdx.x] / fmaxf(cnts[b*32+id], 1.0f);
  }
  __syncthreads();
  const int* mb = imap + (size_t)b*P;
  float* ob = out + (size_t)b*3*P;
  for (int p = blockIdx.x*blockDim.x + threadIdx.x; p < P; p += gridDim.x*blockDim.x){
    int id = mb[p];
    ob[p]     = lm[id*3+0];
    ob[P+p]   = lm[id*3+1];
    ob[2*P+p] = lm[id*3+2];
  }
}

static inline int cdiv(int a, int b){ return (a+b-1)/b; }

extern "C" void kernel_launch(void* const* d_in, const int* in_sizes, int n_in,
                              void* d_out, int out_size, void* d_ws, size_t ws_size,
                              hipStream_t stream) {
  const float* x    = (const float*)d_in[0];
  const int*   imap = (const int*)d_in[1];
  const float* w_in = (const float*)d_in[2];
  const float* b_in = (const float*)d_in[3];
  const float *wd[4], *bd[4], *wu[4], *bu[4];
  for (int i=0;i<4;i++){ wd[i]=(const float*)d_in[4+2*i];  bd[i]=(const float*)d_in[5+2*i]; }
  for (int i=0;i<4;i++){ wu[i]=(const float*)d_in[12+2*i]; bu[i]=(const float*)d_in[13+2*i]; }
  const float* w_out = (const float*)d_in[20];
  const float* b_out = (const float*)d_in[21];
  float* out = (float*)d_out;

  char* ws = (char*)d_ws;
  float* A     = (float*)ws;
  float* Bb    = (float*)(ws + (size_t)134217728);
  float* stats = (float*)(ws + (size_t)134217728 + (size_t)67108864);
  float* stLin = stats;          // 8*16*2  = 256
  float* std0  = stLin + 256;    // 8*32*2  = 512
  float* std1  = std0  + 512;    // 8*64*2  = 1024
  float* std2  = std1  + 1024;   // 8*128*2 = 2048
  float* std3  = std2  + 2048;   // 8*256*2 = 4096
  float* stu0  = std3  + 4096;   // 8*128*2 = 2048
  float* stu1  = stu0  + 2048;   // 8*64*2  = 1024
  float* stu2  = stu1  + 1024;   // 8*32*2  = 512
  float* stu3  = stu2  + 512;    // 8*16*2  = 256
  float* sums  = stu3  + 256;    // [8][32][3] = 768
  float* cnts  = sums  + 768;    // [8][32]    = 256
  hipMemsetAsync(stats, 0, (size_t)(11776 + 1024)*sizeof(float), stream);

  // conv_in: 3 -> 16 @ 512x512 (raw input, emits stLin)
  conv7_in_t<<<2048, 256, 0, stream>>>(x, w_in, b_in, A, stLin);

  // down path (normalize input via statIn, emit statOut)  -- R10 configs
  conv3s2_t<16,8,4,false><<<2048, 256, 0, stream>>>(A,  wd[0], bd[0], Bb, 512, 512, stLin, std0);
  conv3s2_t<32,8,4,false><<<1024, 256, 0, stream>>>(Bb, wd[1], bd[1], A,  256, 256, std0, std1);
  conv3s2_t<64,8,2,true><<<1024, 256, 0, stream>>>(A,  wd[2], bd[2], Bb, 128, 128, std1, std2);
  conv3s2_t<128,4,2,true><<<1024, 256, 0, stream>>>(Bb, wd[3], bd[3], A,  64,  64, std2, std3);

  // up path -- R10 configs
  tconv3_t<256,2><<<1024, 256, 0, stream>>>(A,  wu[0], bu[0], Bb, 32, 32, std3, stu0);
  tconv3_t<128,4><<<1024, 256, 0, stream>>>(Bb, wu[1], bu[1], A,  64, 64, stu0, stu1);
  tconv3_t<64,8><<<1024, 256, 0, stream>>>(A,  wu[2], bu[2], Bb, 128, 128, stu1, stu2);
  tconv3_t<32,8><<<2048, 256, 0, stream>>>(Bb, wu[3], bu[3], A,  256, 256, stu2, stu3);

  // conv_out: 16 -> 3 @ 512x512 + tanh + fused scatter-sum pooling
  conv7_out_t<<<1024, 256, 0, stream>>>(A, w_out, b_out, out, stu3, imap, sums, cnts);

  // broadcast means back
  pool_bcast<<<dim3(128,BATCH),256,0,stream>>>(out, imap, sums, cnts);
}

// Round 15
// 2338.248 us; speedup vs baseline: 1.5292x; 1.0052x over previous
//
#include <hip/hip_runtime.h>
#include <math.h>
#include <type_traits>

#define BATCH 8
#define EPS 1e-5f

__device__ __forceinline__ int refl(int p, int n){ return p<0 ? -p : (p>=n ? 2*n-2-p : p); }

// stat layout per layer: stat[(b*C + c)*2] = sum, +1 = sumsq (atomic-accumulated)

// ---------------- conv_in: 3->16, 7x7, reflect pad 3, 512x512, COT=16, PX=4 ----------------
__global__ __launch_bounds__(256) void conv7_in_t(const float* __restrict__ in,
    const float* __restrict__ w, const float* __restrict__ bias, float* __restrict__ out,
    float* __restrict__ statOut){
  const int H=512, W=512;
  __shared__ float wsm[3*49*16];
  __shared__ float bsm[16];
  __shared__ float red[4][32];
  for (int t=threadIdx.x; t<2352; t+=256){
    int j = t & 15; int r = t >> 4;
    wsm[t] = w[j*147 + r];
  }
  if (threadIdx.x < 16) bsm[threadIdx.x] = bias[threadIdx.x];
  __syncthreads();
  int idx = blockIdx.x*256 + threadIdx.x;
  int xq = idx & 127; int y = (idx >> 7) & 511; int b = idx >> 16;
  int x0 = xq*4;
  bool colInt = (xq >= 1) && (xq <= 126);
  int ry[7];
  #pragma unroll
  for (int k=0;k<7;k++) ry[k]=refl(y+k-3,H);
  float acc[16][4];
  #pragma unroll
  for (int j=0;j<16;j++){ float bv=bsm[j];
    #pragma unroll
    for (int p=0;p<4;p++) acc[j][p]=bv; }
  const float* inb = in + (size_t)b*3*H*W;

  auto run = [&](auto INTC){
    constexpr bool INT = decltype(INTC)::value;
    int rx[10];
    if constexpr (!INT){
      #pragma unroll
      for (int q=0;q<10;q++) rx[q]=refl(x0+q-3,W);
    }
    for (int ci=0; ci<3; ++ci){
      const float* ipc = inb + ci*H*W;
      #pragma unroll
      for (int ky=0; ky<7; ++ky){
        const float* row = ipc + ry[ky]*W;
        float rv[10];
        if constexpr (INT){
          rv[0] = row[x0-3];
          float2 a = *(const float2*)(row + x0-2);
          float4 c = *(const float4*)(row + x0);
          float2 d = *(const float2*)(row + x0+4);
          rv[1]=a.x; rv[2]=a.y;
          rv[3]=c.x; rv[4]=c.y; rv[5]=c.z; rv[6]=c.w;
          rv[7]=d.x; rv[8]=d.y;
          rv[9] = row[x0+6];
        } else {
          #pragma unroll
          for (int q=0;q<10;q++) rv[q] = row[rx[q]];
        }
        #pragma unroll
        for (int kx=0; kx<7; ++kx){
          const float4* wp = (const float4*)&wsm[(ci*49+ky*7+kx)*16];
          float4 w0=wp[0], w1=wp[1], w2=wp[2], w3=wp[3];
          float wv[16] = {w0.x,w0.y,w0.z,w0.w, w1.x,w1.y,w1.z,w1.w,
                          w2.x,w2.y,w2.z,w2.w, w3.x,w3.y,w3.z,w3.w};
          #pragma unroll
          for (int p=0;p<4;p++){
            float iv = rv[kx+p];
            #pragma unroll
            for (int j=0;j<16;j++) acc[j][p] = fmaf(iv, wv[j], acc[j][p]);
          }
        }
      }
    }
  };
  if (colInt) run(std::true_type{}); else run(std::false_type{});

  float* ob = out + ((size_t)(b*16)*H + y)*W + x0;
  #pragma unroll
  for (int j=0;j<16;j++){
    float4 v = {acc[j][0],acc[j][1],acc[j][2],acc[j][3]};
    *(float4*)(ob + (size_t)j*H*W) = v;
  }
  // ---- stats ----
  float ss[16], qq[16];
  #pragma unroll
  for (int j=0;j<16;j++){
    float a=0.f,c=0.f;
    #pragma unroll
    for (int p=0;p<4;p++){ a+=acc[j][p]; c=fmaf(acc[j][p],acc[j][p],c); }
    ss[j]=a; qq[j]=c;
  }
  #pragma unroll
  for (int o=32;o>0;o>>=1){
    #pragma unroll
    for (int j=0;j<16;j++){ ss[j]+=__shfl_down(ss[j],o); qq[j]+=__shfl_down(qq[j],o); }
  }
  int lane = threadIdx.x & 63, wid = threadIdx.x >> 6;
  if (lane==0){
    #pragma unroll
    for (int j=0;j<16;j++){ red[wid][j]=ss[j]; red[wid][16+j]=qq[j]; }
  }
  __syncthreads();
  if (threadIdx.x < 16){
    int j = threadIdx.x;
    float a = red[0][j]+red[1][j]+red[2][j]+red[3][j];
    float c = red[0][16+j]+red[1][16+j]+red[2][16+j]+red[3][16+j];
    float* sp = &statOut[((size_t)b*16 + j)*2];
    atomicAdd(sp, a); atomicAdd(sp+1, c);
  }
}

// ---------------- conv_out: 16->3, 7x7 reflect, tanh, PX=4; normalizes input ----------------
// Fused per-(b,id) scatter-sum epilogue. PX=4 @ 2048 blocks (R15: occupancy unlock vs PX=8 @1024).
__global__ __launch_bounds__(256) void conv7_out_t(const float* __restrict__ in,
    const float* __restrict__ w, const float* __restrict__ bias, float* __restrict__ out,
    const float* __restrict__ statIn, const int* __restrict__ imap,
    float* __restrict__ sums, float* __restrict__ cnts){
  const int H=512, W=512;
  __shared__ float wsm[16*49*3];
  __shared__ float bsm[3];
  __shared__ float msm[16], ism[16];
  __shared__ float ls[96];
  __shared__ float lc[32];
  for (int t=threadIdx.x; t<2352; t+=256){
    int j = t % 3; int r = t / 3;
    wsm[t] = w[j*784 + r];
  }
  if (threadIdx.x < 3) bsm[threadIdx.x] = bias[threadIdx.x];
  if (threadIdx.x < 96) ls[threadIdx.x] = 0.f;
  if (threadIdx.x >= 96 && threadIdx.x < 128) lc[threadIdx.x-96] = 0.f;
  int idx = blockIdx.x*256 + threadIdx.x;
  int xq = idx & 127; int y = (idx >> 7) & 511; int b = idx >> 16;
  if (threadIdx.x < 16){
    const float invHW = 1.f/(512.f*512.f);
    float s  = statIn[((size_t)b*16 + threadIdx.x)*2];
    float s2 = statIn[((size_t)b*16 + threadIdx.x)*2+1];
    float m = s*invHW;
    float v = fmaxf(s2*invHW - m*m, 0.f);
    msm[threadIdx.x] = m; ism[threadIdx.x] = rsqrtf(v + EPS);
  }
  __syncthreads();
  int x0 = xq*4;
  bool colInt = (xq >= 1) && (xq <= 126);
  int ry[7];
  #pragma unroll
  for (int k=0;k<7;k++) ry[k]=refl(y+k-3,H);
  float acc[3][4];
  #pragma unroll
  for (int j=0;j<3;j++){ float bv=bsm[j];
    #pragma unroll
    for (int p=0;p<4;p++) acc[j][p]=bv; }
  const float* inb = in + (size_t)b*16*H*W;

  auto run = [&](auto INTC){
    constexpr bool INT = decltype(INTC)::value;
    int rx[10];
    if constexpr (!INT){
      #pragma unroll
      for (int q=0;q<10;q++) rx[q]=refl(x0+q-3,W);
    }
    for (int ci=0; ci<16; ++ci){
      const float* ipc = inb + (size_t)ci*H*W;
      float m = msm[ci], is = ism[ci];
      #pragma unroll
      for (int ky=0; ky<7; ++ky){
        const float* row = ipc + ry[ky]*W;
        float rv[10];
        if constexpr (INT){
          rv[0] = row[x0-3];
          float2 a = *(const float2*)(row + x0-2);
          float4 c = *(const float4*)(row + x0);
          float2 d = *(const float2*)(row + x0+4);
          rv[1]=a.x; rv[2]=a.y;
          rv[3]=c.x; rv[4]=c.y; rv[5]=c.z; rv[6]=c.w;
          rv[7]=d.x; rv[8]=d.y;
          rv[9] = row[x0+6];
        } else {
          #pragma unroll
          for (int q=0;q<10;q++) rv[q] = row[rx[q]];
        }
        #pragma unroll
        for (int q=0;q<10;q++) rv[q] = fmaxf((rv[q]-m)*is, 0.f);
        #pragma unroll
        for (int kx=0; kx<7; ++kx){
          const float* wp = &wsm[(ci*49+ky*7+kx)*3];
          float w0=wp[0], w1=wp[1], w2=wp[2];
          #pragma unroll
          for (int p=0;p<4;p++){
            float iv = rv[kx+p];
            acc[0][p] = fmaf(iv, w0, acc[0][p]);
            acc[1][p] = fmaf(iv, w1, acc[1][p]);
            acc[2][p] = fmaf(iv, w2, acc[2][p]);
          }
        }
      }
    }
  };
  if (colInt) run(std::true_type{}); else run(std::false_type{});

  // tanh + store
  #pragma unroll
  for (int j=0;j<3;j++)
    #pragma unroll
    for (int p=0;p<4;p++) acc[j][p] = tanhf(acc[j][p]);

  float* ob = out + ((size_t)(b*3)*H + y)*W + x0;
  #pragma unroll
  for (int j=0;j<3;j++){
    float4 v0 = {acc[j][0],acc[j][1],acc[j][2],acc[j][3]};
    *(float4*)(ob + (size_t)j*H*W) = v0;
  }

  // ---- fused scatter-sum pooling epilogue ----
  const int* mb = imap + ((size_t)b*H + y)*W + x0;
  int4 i0 = *(const int4*)(mb);
  int im[4] = {i0.x,i0.y,i0.z,i0.w};
  #pragma unroll
  for (int p=0;p<4;p++){
    int id = im[p];
    atomicAdd(&ls[id*3+0], acc[0][p]);
    atomicAdd(&ls[id*3+1], acc[1][p]);
    atomicAdd(&ls[id*3+2], acc[2][p]);
    atomicAdd(&lc[id], 1.0f);
  }
  __syncthreads();
  if (threadIdx.x < 96) atomicAdd(&sums[b*96+threadIdx.x], ls[threadIdx.x]);
  if (threadIdx.x >= 96 && threadIdx.x < 128) atomicAdd(&cnts[b*32+threadIdx.x-96], lc[threadIdx.x-96]);
}

// ---------------- 3x3 stride-2 conv, pad 1; normalizes input, emits stats ----------------
// Scalar (s_load) weights via wave-uniform index; optional 2-deep ci software pipeline.
// PIPE only safe when rv buffer small (PX=2); PIPE+PX=4 spills (R12: 890MB FETCH).
template<int CIN, int COT, int PX, bool PIPE>
__global__ __launch_bounds__(256,4) void conv3s2_t(const float* __restrict__ in,
    const float* __restrict__ w, const float* __restrict__ bias, float* __restrict__ out,
    int Hin, int Win, const float* __restrict__ statIn, float* __restrict__ statOut){
  const int Cout = 2*CIN;
  __shared__ float msm[CIN], ism[CIN];
  __shared__ float red[4][2*COT];
  int Hout = Hin>>1, Wout = Win>>1, WQ = Wout/PX;
  int idx = blockIdx.x*256 + threadIdx.x;
  int xq = idx % WQ; int t = idx / WQ;
  int y  = t % Hout;  t /= Hout;
  int cot = t % (Cout/COT); int b = t / (Cout/COT);
  int co0 = __builtin_amdgcn_readfirstlane(cot) * COT;   // wave-uniform
  {
    float invHW = 1.f/(float)(Hin*Win);
    for (int t2=threadIdx.x; t2<CIN; t2+=256){
      float s  = statIn[((size_t)b*CIN + t2)*2];
      float s2 = statIn[((size_t)b*CIN + t2)*2+1];
      float m = s*invHW;
      float v = fmaxf(s2*invHW - m*m, 0.f);
      msm[t2] = m; ism[t2] = rsqrtf(v + EPS);
    }
  }
  __syncthreads();
  int x0 = xq*PX; int ix0 = 2*x0-1; int iy0 = 2*y-1;
  bool colInt = (xq >= 1);
  float acc[COT][PX];
  #pragma unroll
  for (int j=0;j<COT;j++){ float bv = bias[co0+j];
    #pragma unroll
    for (int p=0;p<PX;p++) acc[j][p]=bv; }
  const float* inb = in + (size_t)b*CIN*Hin*Win;

  auto loadci = [&](int ci, float (&rv)[3][2*PX+1]){
    const float* ip = inb + (size_t)ci*Hin*Win;
    float m = msm[ci], is = ism[ci];
    #pragma unroll
    for (int ky=0;ky<3;ky++){
      int iy = iy0+ky;
      bool okY = (unsigned)iy < (unsigned)Hin;
      const float* row = ip + iy*Win;
      if (okY && colInt){
        rv[ky][0] = row[ix0];
        if constexpr (PX>=2){
          float4 a = *(const float4*)(row + ix0+1);
          rv[ky][1]=a.x; rv[ky][2]=a.y; rv[ky][3]=a.z; rv[ky][4]=a.w;
        } else {
          float2 a = *(const float2*)(row + ix0+1);
          rv[ky][1]=a.x; rv[ky][2]=a.y;
        }
        if constexpr (PX==4){
          float4 b4 = *(const float4*)(row + ix0+5);
          rv[ky][5]=b4.x; rv[ky][6]=b4.y; rv[ky][7]=b4.z; rv[ky][8]=b4.w;
        }
        #pragma unroll
        for (int q=0;q<2*PX+1;q++) rv[ky][q] = fmaxf((rv[ky][q]-m)*is, 0.f);
      } else {
        #pragma unroll
        for (int q=0;q<2*PX+1;q++){
          int ix = ix0+q;
          rv[ky][q] = (okY && (unsigned)ix<(unsigned)Win) ? fmaxf((row[ix]-m)*is,0.f) : 0.f;
        }
      }
    }
  };
  auto compci = [&](int ci, float (&rv)[3][2*PX+1]){
    #pragma unroll
    for (int j=0;j<COT;j++){
      const float* wj = w + ((size_t)(co0+j)*CIN + ci)*9;   // uniform -> s_load
      float wk[9];
      #pragma unroll
      for (int k=0;k<9;k++) wk[k] = wj[k];
      #pragma unroll
      for (int p=0;p<PX;p++)
        #pragma unroll
        for (int ky=0;ky<3;ky++)
          #pragma unroll
          for (int kx=0;kx<3;kx++)
            acc[j][p] = fmaf(rv[ky][2*p+kx], wk[ky*3+kx], acc[j][p]);
    }
  };

  if constexpr (PIPE){
    float rvA[3][2*PX+1], rvB[3][2*PX+1];
    loadci(0, rvA);
    for (int ci=0; ci<CIN; ci+=2){
      loadci(ci+1, rvB);
      compci(ci, rvA);
      if (ci+2 < CIN) loadci(ci+2, rvA);
      compci(ci+1, rvB);
    }
  } else {
    for (int ci=0; ci<CIN; ++ci){
      float rv[3][2*PX+1];
      loadci(ci, rv);
      compci(ci, rv);
    }
  }

  float* ob = out + (((size_t)b*Cout + co0)*Hout + y)*Wout + x0;
  #pragma unroll
  for (int j=0;j<COT;j++){
    if constexpr (PX==4){
      float4 v = {acc[j][0],acc[j][1],acc[j][2],acc[j][3]};
      *(float4*)(ob + (size_t)j*Hout*Wout) = v;
    } else if constexpr (PX==2){
      float2 v = {acc[j][0],acc[j][1]};
      *(float2*)(ob + (size_t)j*Hout*Wout) = v;
    } else {
      ob[(size_t)j*Hout*Wout] = acc[j][0];
    }
  }
  // ---- stats ----
  float ss[COT], qq[COT];
  #pragma unroll
  for (int j=0;j<COT;j++){
    float a=0.f,c=0.f;
    #pragma unroll
    for (int p=0;p<PX;p++){ a+=acc[j][p]; c=fmaf(acc[j][p],acc[j][p],c); }
    ss[j]=a; qq[j]=c;
  }
  #pragma unroll
  for (int o=32;o>0;o>>=1){
    #pragma unroll
    for (int j=0;j<COT;j++){ ss[j]+=__shfl_down(ss[j],o); qq[j]+=__shfl_down(qq[j],o); }
  }
  int lane = threadIdx.x & 63, wid = threadIdx.x >> 6;
  if (lane==0){
    #pragma unroll
    for (int j=0;j<COT;j++){ red[wid][j]=ss[j]; red[wid][COT+j]=qq[j]; }
  }
  __syncthreads();
  if (threadIdx.x < COT){
    int j = threadIdx.x;
    float a = red[0][j]+red[1][j]+red[2][j]+red[3][j];
    float c = red[0][COT+j]+red[1][COT+j]+red[2][COT+j]+red[3][COT+j];
    float* sp = &statOut[((size_t)b*Cout + co0 + j)*2];
    atomicAdd(sp, a); atomicAdd(sp+1, c);
  }
}

// ---------------- tconv k=3 s=2 p=1 op=1; scalar weights; 2-deep ci pipeline ----------------
template<int CIN, int COT>
__global__ __launch_bounds__(256,4) void tconv3_t(const float* __restrict__ in,
    const float* __restrict__ w, const float* __restrict__ bias, float* __restrict__ out,
    int Hin, int Win, const float* __restrict__ statIn, float* __restrict__ statOut){
  const int PX=2, Cout = CIN/2;
  __shared__ float msm[CIN], ism[CIN];
  __shared__ float red[4][2*COT];
  int Hout = Hin*2, Wout = Win*2, WQ = Win/PX;
  int idx = blockIdx.x*256 + threadIdx.x;
  int xq = idx % WQ; int t = idx / WQ;
  int yo = t % Hin;  t /= Hin;
  int cot = t % (Cout/COT); int b = t / (Cout/COT);
  int co0 = __builtin_amdgcn_readfirstlane(cot) * COT;  // wave-uniform
  {
    float invHW = 1.f/(float)(Hin*Win);
    for (int t2=threadIdx.x; t2<CIN; t2+=256){
      float s  = statIn[((size_t)b*CIN + t2)*2];
      float s2 = statIn[((size_t)b*CIN + t2)*2+1];
      float m = s*invHW;
      float v = fmaxf(s2*invHW - m*m, 0.f);
      msm[t2] = m; ism[t2] = rsqrtf(v + EPS);
    }
  }
  __syncthreads();
  int xo0 = xq*PX;
  bool okY1 = (yo+1) < Hin;
  bool fast = okY1 && (xo0+2 < Win);
  float acc[COT][2][2*PX];
  #pragma unroll
  for (int j=0;j<COT;j++){ float bv = bias[co0+j];
    #pragma unroll
    for (int oy=0;oy<2;oy++)
      #pragma unroll
      for (int ox=0;ox<2*PX;ox++) acc[j][oy][ox]=bv; }
  const float* inb = in + (size_t)b*CIN*Hin*Win;

  auto loadci = [&](int ci, float (&v)[2][PX+1]){
    const float* ip = inb + (size_t)ci*Hin*Win + (size_t)yo*Win;
    float m = msm[ci], is = ism[ci];
    if (fast){
      float2 a = *(const float2*)(ip + xo0);
      float2 b2 = *(const float2*)(ip + Win + xo0);
      v[0][0]=a.x;  v[0][1]=a.y;  v[0][2]=ip[xo0+2];
      v[1][0]=b2.x; v[1][1]=b2.y; v[1][2]=ip[Win+xo0+2];
      #pragma unroll
      for (int r=0;r<2;r++)
        #pragma unroll
        for (int c=0;c<3;c++) v[r][c] = fmaxf((v[r][c]-m)*is, 0.f);
    } else {
      #pragma unroll
      for (int c=0;c<PX+1;c++){
        int xc = xo0+c; bool okX = xc < Win;
        v[0][c] = okX ? fmaxf((ip[xc]-m)*is,0.f) : 0.f;
        v[1][c] = (okX && okY1) ? fmaxf((ip[Win+xc]-m)*is,0.f) : 0.f;
      }
    }
  };
  auto compci = [&](int ci, float (&v)[2][PX+1]){
    #pragma unroll
    for (int j=0;j<COT;j++){
      const float* wj = w + ((size_t)ci*Cout + co0+j)*9;   // uniform -> s_load
      float wk[9];
      #pragma unroll
      for (int k=0;k<9;k++) wk[k] = wj[k];
      #pragma unroll
      for (int q=0;q<PX;q++){
        float v00=v[0][q], v01=v[0][q+1], v10=v[1][q], v11=v[1][q+1];
        acc[j][0][2*q]   = fmaf(v00, wk[4], acc[j][0][2*q]);
        acc[j][0][2*q+1] = fmaf(v00, wk[5], fmaf(v01, wk[3], acc[j][0][2*q+1]));
        acc[j][1][2*q]   = fmaf(v00, wk[7], fmaf(v10, wk[1], acc[j][1][2*q]));
        acc[j][1][2*q+1] = fmaf(v00, wk[8], fmaf(v01, wk[6],
                           fmaf(v10, wk[2], fmaf(v11, wk[0], acc[j][1][2*q+1]))));
      }
    }
  };

  float vA[2][PX+1], vB[2][PX+1];
  loadci(0, vA);
  for (int ci=0; ci<CIN; ci+=2){
    loadci(ci+1, vB);
    compci(ci, vA);
    if (ci+2 < CIN) loadci(ci+2, vA);
    compci(ci+1, vB);
  }

  float* ob = out + (((size_t)b*Cout + co0)*Hout + 2*yo)*Wout + 2*xo0;
  #pragma unroll
  for (int j=0;j<COT;j++){
    float4 r0 = {acc[j][0][0],acc[j][0][1],acc[j][0][2],acc[j][0][3]};
    float4 r1 = {acc[j][1][0],acc[j][1][1],acc[j][1][2],acc[j][1][3]};
    *(float4*)(ob + (size_t)j*Hout*Wout)        = r0;
    *(float4*)(ob + (size_t)j*Hout*Wout + Wout) = r1;
  }
  // ---- stats ----
  float ss[COT], qq[COT];
  #pragma unroll
  for (int j=0;j<COT;j++){
    float a=0.f,c=0.f;
    #pragma unroll
    for (int oy=0;oy<2;oy++)
      #pragma unroll
      for (int ox=0;ox<2*PX;ox++){ float u=acc[j][oy][ox]; a+=u; c=fmaf(u,u,c); }
    ss[j]=a; qq[j]=c;
  }
  #pragma unroll
  for (int o=32;o>0;o>>=1){
    #pragma unroll
    for (int j=0;j<COT;j++){ ss[j]+=__shfl_down(ss[j],o); qq[j]+=__shfl_down(qq[j],o); }
  }
  int lane = threadIdx.x & 63, wid = threadIdx.x >> 6;
  if (lane==0){
    #pragma unroll
    for (int j=0;j<COT;j++){ red[wid][j]=ss[j]; red[wid][COT+j]=qq[j]; }
  }
  __syncthreads();
  if (threadIdx.x < COT){
    int j = threadIdx.x;
    float a = red[0][j]+red[1][j]+red[2][j]+red[3][j];
    float c = red[0][COT+j]+red[1][COT+j]+red[2][COT+j]+red[3][COT+j];
    float* sp = &statOut[((size_t)b*Cout + co0 + j)*2];
    atomicAdd(sp, a); atomicAdd(sp+1, c);
  }
}

// ---------------- broadcast means back ----------------
__global__ void pool_bcast(float* __restrict__ out, const int* __restrict__ imap,
                           const float* __restrict__ sums, const float* __restrict__ cnts){
  const int P = 512*512;
  int b = blockIdx.y;
  __shared__ float lm[96];
  if (threadIdx.x < 96){
    int id = threadIdx.x/3;
    lm[threadIdx.x] = sums[b*96+threadIdx.x] / fmaxf(cnts[b*32+id], 1.0f);
  }
  __syncthreads();
  const int* mb = imap + (size_t)b*P;
  float* ob = out + (size_t)b*3*P;
  for (int p = blockIdx.x*blockDim.x + threadIdx.x; p < P; p += gridDim.x*blockDim.x){
    int id = mb[p];
    ob[p]     = lm[id*3+0];
    ob[P+p]   = lm[id*3+1];
    ob[2*P+p] = lm[id*3+2];
  }
}

static inline int cdiv(int a, int b){ return (a+b-1)/b; }

extern "C" void kernel_launch(void* const* d_in, const int* in_sizes, int n_in,
                              void* d_out, int out_size, void* d_ws, size_t ws_size,
                              hipStream_t stream) {
  const float* x    = (const float*)d_in[0];
  const int*   imap = (const int*)d_in[1];
  const float* w_in = (const float*)d_in[2];
  const float* b_in = (const float*)d_in[3];
  const float *wd[4], *bd[4], *wu[4], *bu[4];
  for (int i=0;i<4;i++){ wd[i]=(const float*)d_in[4+2*i];  bd[i]=(const float*)d_in[5+2*i]; }
  for (int i=0;i<4;i++){ wu[i]=(const float*)d_in[12+2*i]; bu[i]=(const float*)d_in[13+2*i]; }
  const float* w_out = (const float*)d_in[20];
  const float* b_out = (const float*)d_in[21];
  float* out = (float*)d_out;

  char* ws = (char*)d_ws;
  float* A     = (float*)ws;
  float* Bb    = (float*)(ws + (size_t)134217728);
  float* stats = (float*)(ws + (size_t)134217728 + (size_t)67108864);
  float* stLin = stats;          // 8*16*2  = 256
  float* std0  = stLin + 256;    // 8*32*2  = 512
  float* std1  = std0  + 512;    // 8*64*2  = 1024
  float* std2  = std1  + 1024;   // 8*128*2 = 2048
  float* std3  = std2  + 2048;   // 8*256*2 = 4096
  float* stu0  = std3  + 4096;   // 8*128*2 = 2048
  float* stu1  = stu0  + 2048;   // 8*64*2  = 1024
  float* stu2  = stu1  + 1024;   // 8*32*2  = 512
  float* stu3  = stu2  + 512;    // 8*16*2  = 256
  float* sums  = stu3  + 256;    // [8][32][3] = 768
  float* cnts  = sums  + 768;    // [8][32]    = 256
  hipMemsetAsync(stats, 0, (size_t)(11776 + 1024)*sizeof(float), stream);

  // conv_in: 3 -> 16 @ 512x512 (raw input, emits stLin)
  conv7_in_t<<<2048, 256, 0, stream>>>(x, w_in, b_in, A, stLin);

  // down path (normalize input via statIn, emit statOut)  -- R10 configs
  conv3s2_t<16,8,4,false><<<2048, 256, 0, stream>>>(A,  wd[0], bd[0], Bb, 512, 512, stLin, std0);
  conv3s2_t<32,8,4,false><<<1024, 256, 0, stream>>>(Bb, wd[1], bd[1], A,  256, 256, std0, std1);
  conv3s2_t<64,8,2,true><<<1024, 256, 0, stream>>>(A,  wd[2], bd[2], Bb, 128, 128, std1, std2);
  conv3s2_t<128,4,2,true><<<1024, 256, 0, stream>>>(Bb, wd[3], bd[3], A,  64,  64, std2, std3);

  // up path -- R10 configs
  tconv3_t<256,2><<<1024, 256, 0, stream>>>(A,  wu[0], bu[0], Bb, 32, 32, std3, stu0);
  tconv3_t<128,4><<<1024, 256, 0, stream>>>(Bb, wu[1], bu[1], A,  64, 64, stu0, stu1);
  tconv3_t<64,8><<<1024, 256, 0, stream>>>(A,  wu[2], bu[2], Bb, 128, 128, stu1, stu2);
  tconv3_t<32,8><<<2048, 256, 0, stream>>>(Bb, wu[3], bu[3], A,  256, 256, stu2, stu3);

  // conv_out: 16 -> 3 @ 512x512 + tanh + fused scatter-sum pooling (PX=4, 2048 blocks)
  conv7_out_t<<<2048, 256, 0, stream>>>(A, w_out, b_out, out, stu3, imap, sums, cnts);

  // broadcast means back
  pool_bcast<<<dim3(128,BATCH),256,0,stream>>>(out, imap, sums, cnts);
}